// Round 4
// baseline (252.267 us; speedup 1.0000x reference)
//
#include <hip/hip_runtime.h>

// ---------------------------------------------------------------------------
// GIN: 3 x (bucket gather-sum + (x+agg)@W + b, relu) + MLP head, bf16 MFMA.
// r10: DMA gather via global_load_lds (fire-and-forget, no VGPR return).
//     Evidence r6/r8/r9: gather time = instrs x 188cyc/CU FLAT -- invariant
//     to bytes, lines/instr, and waves => per-CU scattered vmem instrs with
//     VGPR destinations complete serially at ~L2 latency. global_load_lds
//     has no VGPR dest (vmcnt-counted DMA, per-lane global src) -> stage all
//     bucket rows to LDS back-to-back, one barrier, decode from LDS.
//     32-node buckets: <=512 edges = 64KB dyn LDS + ~11KB static -> 2 blk/CU.
//     Tail edges padded with zero-row index N (row N of xq/h1q/h2q zeroed).
//     6 dispatches: prep_all, bin_edges, sort_buckets, 2x fused_layer,
//     fused_l3_head.
// ---------------------------------------------------------------------------

typedef short short8 __attribute__((ext_vector_type(8)));
typedef float v4f __attribute__((ext_vector_type(4)));
typedef float v2f __attribute__((ext_vector_type(2)));

#define NPB 32      // nodes per bucket
#define BCAP 512    // bucket capacity: mean 384, expected max ~455
#define MAXB 2048   // >= nbuckets (1563)
#define DYN_LDS 66560  // 520 rows x 128B staged fp8

__device__ inline unsigned short f2bf(float f) {
  union { float f; unsigned int u; } c; c.f = f;
  unsigned int u = c.u;
  return (unsigned short)((u + 0x7fffu + ((u >> 16) & 1u)) >> 16);  // RNE
}
__device__ inline float bfbits2f(unsigned int hi) {
  union { unsigned int u; float f; } c; c.u = hi; return c.f;
}
__device__ inline unsigned int pack2(float a, float b) {
  return (unsigned int)f2bf(a) | ((unsigned int)f2bf(b) << 16);
}
__device__ inline void add8(float* s, uint4 v) {
  s[0] += bfbits2f(v.x << 16); s[1] += bfbits2f(v.x & 0xffff0000u);
  s[2] += bfbits2f(v.y << 16); s[3] += bfbits2f(v.y & 0xffff0000u);
  s[4] += bfbits2f(v.z << 16); s[5] += bfbits2f(v.z & 0xffff0000u);
  s[6] += bfbits2f(v.w << 16); s[7] += bfbits2f(v.w & 0xffff0000u);
}
// decode 16 fp8 (e4m3, HW format) and accumulate into s[0..15]
__device__ inline void addf8q(float* s, uint4 v) {
  v2f p;
  p = __builtin_amdgcn_cvt_pk_f32_fp8(v.x, false); s[0]  += p.x; s[1]  += p.y;
  p = __builtin_amdgcn_cvt_pk_f32_fp8(v.x, true);  s[2]  += p.x; s[3]  += p.y;
  p = __builtin_amdgcn_cvt_pk_f32_fp8(v.y, false); s[4]  += p.x; s[5]  += p.y;
  p = __builtin_amdgcn_cvt_pk_f32_fp8(v.y, true);  s[6]  += p.x; s[7]  += p.y;
  p = __builtin_amdgcn_cvt_pk_f32_fp8(v.z, false); s[8]  += p.x; s[9]  += p.y;
  p = __builtin_amdgcn_cvt_pk_f32_fp8(v.z, true);  s[10] += p.x; s[11] += p.y;
  p = __builtin_amdgcn_cvt_pk_f32_fp8(v.w, false); s[12] += p.x; s[13] += p.y;
  p = __builtin_amdgcn_cvt_pk_f32_fp8(v.w, true);  s[14] += p.x; s[15] += p.y;
}
__device__ inline unsigned char f2fp8(float v) {
  return (unsigned char)(__builtin_amdgcn_cvt_pk_fp8_f32(v, v, 0, false) & 0xff);
}
__device__ inline int wave_incl_scan_int(int v, int lane) {
#pragma unroll
  for (int off = 1; off < 64; off <<= 1) {
    int t = __shfl_up(v, off, 64);
    if (lane >= off) v += t;
  }
  return v;
}

// ------------------------- prep: weights + x->bf16/fp8 + zero bcnt ----------
__global__ __launch_bounds__(256) void prep_all(
    const float* __restrict__ W0, const float* __restrict__ W1, const float* __restrict__ W2,
    const float* __restrict__ Wm1, const float* __restrict__ Wm2,
    unsigned short* __restrict__ W0T, unsigned short* __restrict__ W1T,
    unsigned short* __restrict__ W2T, unsigned short* __restrict__ Wm1T,
    unsigned short* __restrict__ Wm2T,
    const float* __restrict__ x, unsigned short* __restrict__ xb,
    unsigned char* __restrict__ xq, unsigned char* __restrict__ h1q,
    unsigned char* __restrict__ h2q, int n8,
    int* __restrict__ bcnt) {
  int i = blockIdx.x * 256 + threadIdx.x;
  int N = n8 >> 4;
  if (i < MAXB) bcnt[i] = 0;
  if (i < 48) {  // zero the pad row (index N) of all three fp8 arrays
    int a = i >> 4, sl = i & 15;
    unsigned char* q = (a == 0) ? xq : (a == 1) ? h1q : h2q;
    uint2 z; z.x = 0; z.y = 0;
    ((uint2*)(q + (size_t)N * 128))[sl] = z;
  }
  if (i < n8) {
    const float4* p = (const float4*)x;
    float4 a = p[2 * (size_t)i], b = p[2 * (size_t)i + 1];
    uint4 o;
    o.x = pack2(a.x, a.y); o.y = pack2(a.z, a.w);
    o.z = pack2(b.x, b.y); o.w = pack2(b.z, b.w);
    ((uint4*)xb)[i] = o;
    unsigned int lo = 0, hi = 0;
    lo = __builtin_amdgcn_cvt_pk_fp8_f32(a.x, a.y, lo, false);
    lo = __builtin_amdgcn_cvt_pk_fp8_f32(a.z, a.w, lo, true);
    hi = __builtin_amdgcn_cvt_pk_fp8_f32(b.x, b.y, hi, false);
    hi = __builtin_amdgcn_cvt_pk_fp8_f32(b.z, b.w, hi, true);
    uint2 q; q.x = lo; q.y = hi;
    ((uint2*)xq)[i] = q;
  }
  if (i < 49152) {                       // 3 x [128,128] -> [128n][128k]
    int w = i / 16384, r = i % 16384;
    int nn = r >> 7, k = r & 127;
    const float* W = (w == 0) ? W0 : (w == 1) ? W1 : W2;
    unsigned short* O = (w == 0) ? W0T : (w == 1) ? W1T : W2T;
    O[r] = f2bf(W[k * 128 + nn]);
  } else if (i < 49152 + 32768) {        // Wm1 [128,256] -> [256n][128k]
    int r = i - 49152;
    int nn = r >> 7, k = r & 127;
    Wm1T[r] = f2bf(Wm1[k * 256 + nn]);
  } else if (i < 49152 + 32768 + 4096) { // Wm2 [256,10] -> [16n][256k], pad 0
    int r = i - 49152 - 32768;
    int nn = r >> 8, k = r & 255;
    Wm2T[r] = (nn < 10) ? f2bf(Wm2[k * 10 + nn]) : (unsigned short)0;
  }
}

// ------------------------- bin edges into 32-node buckets -------------------
// entry = (src << 5) | (dst & 31); bucket = dst >> 5.
__global__ __launch_bounds__(256) void bin_edges(
    const int* __restrict__ src, const int* __restrict__ dst, int E, int per,
    int* __restrict__ bcnt, int* __restrict__ bucketA, int nbuckets) {
  __shared__ int hist[MAXB];
  __shared__ int base[MAXB];
  const int tid = threadIdx.x;
  const int e0 = blockIdx.x * per;
  const int e1 = (e0 + per < E) ? e0 + per : E;
  for (int j = tid; j < nbuckets; j += 256) hist[j] = 0;
  __syncthreads();
  for (int i = e0 + tid; i < e1; i += 256) atomicAdd(&hist[dst[i] >> 5], 1);
  __syncthreads();
  for (int j = tid; j < nbuckets; j += 256) {
    int h = hist[j];
    base[j] = h ? atomicAdd(&bcnt[j], h) : 0;
  }
  __syncthreads();
  for (int i = e0 + tid; i < e1; i += 256) {
    int d = dst[i], s = src[i];
    int b = d >> 5;
    int r = atomicAdd(&base[b], 1);
    bucketA[(size_t)b * BCAP + r] = (s << 5) | (d & 31);
  }
}

// ------------------------- per-bucket counting sort (once) ------------------
__global__ __launch_bounds__(256) void sort_buckets(
    const int* __restrict__ bcnt, const int* __restrict__ bucketA,
    int* __restrict__ srcsS, int* __restrict__ boffs) {
  __shared__ int rawE[BCAP];
  __shared__ int hist[NPB], cur[NPB], offs[NPB + 1];
  const int tid = threadIdx.x;
  const int b = blockIdx.x;
  const int cnt = bcnt[b];
  for (int i = tid; i < cnt; i += 256) rawE[i] = bucketA[(size_t)b * BCAP + i];
  if (tid < NPB) hist[tid] = 0;
  __syncthreads();
  for (int i = tid; i < cnt; i += 256) atomicAdd(&hist[rawE[i] & 31], 1);
  __syncthreads();
  if (tid < NPB) {
    int v = hist[tid];
    int incl = wave_incl_scan_int(v, tid);
    offs[tid] = incl - v;
    cur[tid] = incl - v;
    if (tid == NPB - 1) offs[NPB] = incl;
  }
  __syncthreads();
  for (int i = tid; i < cnt; i += 256) {
    int e = rawE[i];
    int p = atomicAdd(&cur[e & 31], 1);
    srcsS[(size_t)b * BCAP + p] = e >> 5;
  }
  if (tid < NPB + 1) boffs[b * (NPB + 1) + tid] = offs[tid];
}

// ------------------------- DMA gather (shared by both layer kernels) --------
// Stage all cnt sorted neighbor rows (128B fp8 each) into dyn LDS via
// global_load_lds: instr i moves 8 rows; per-lane global src, linear LDS
// dest (HW adds lane*16 to the wave-uniform base). Then decode from LDS:
// thread (g=tid>>3, l=tid&7) accumulates slice l of node g over its edges.
__device__ inline void dma_gather(
    char* dyn, const int* srcS, const int* offs, int cnt, int nI,
    const unsigned short* X, const unsigned char* Xq, int blk, int M,
    unsigned short* As, int tid, int lane) {
  const int wv = tid >> 6;
  const int sl = lane >> 3, ll = lane & 7;
  for (int i = wv; i < nI; i += 4) {
    int r = srcS[i * 8 + sl];
    const char* gp = (const char*)Xq + (size_t)r * 128 + ll * 16;
    __builtin_amdgcn_global_load_lds((const unsigned int*)gp,
                                     (unsigned int*)(dyn + (size_t)i * 1024),
                                     16, 0, 0);
  }
  __syncthreads();  // compiler drains vmcnt before the barrier

  const int l = tid & 7, g = tid >> 3;
  const int node = blk + g;
  const uint4* rows = (const uint4*)dyn;
  const uint4* base = (const uint4*)X;
  float s[16] = {0, 0, 0, 0, 0, 0, 0, 0, 0, 0, 0, 0, 0, 0, 0, 0};
  if (node < M) {
    add8(s, base[(size_t)node * 16 + l * 2]);
    add8(s + 8, base[(size_t)node * 16 + l * 2 + 1]);
  }
  const int beg = offs[g], c = offs[g + 1] - offs[g];
#pragma unroll 4
  for (int j = 0; j < c; ++j) {
    uint4 v = rows[(size_t)(beg + j) * 8 + l];
    addf8q(s, v);
  }
  uint4 o0, o1;
  o0.x = pack2(s[0], s[1]);   o0.y = pack2(s[2], s[3]);
  o0.z = pack2(s[4], s[5]);   o0.w = pack2(s[6], s[7]);
  o1.x = pack2(s[8], s[9]);   o1.y = pack2(s[10], s[11]);
  o1.z = pack2(s[12], s[13]); o1.w = pack2(s[14], s[15]);
  *(uint4*)&As[g * 136 + l * 16] = o0;
  *(uint4*)&As[g * 136 + l * 16 + 8] = o1;
}

// ------------------------- fused layer (layers 1,2) -------------------------
__global__ __launch_bounds__(256) void fused_layer(
    const unsigned short* __restrict__ X, const unsigned char* __restrict__ Xq,
    const int* __restrict__ bcnt,
    const int* __restrict__ srcsS, const int* __restrict__ boffs,
    const unsigned short* __restrict__ BT, const float* __restrict__ bias,
    unsigned short* __restrict__ C, unsigned char* __restrict__ Cq,
    int M, int ZROW) {
  extern __shared__ __align__(16) char dyn[];   // 520 x 128B staged rows
  __shared__ __align__(16) unsigned short As[NPB * 136];
  __shared__ int srcS[520];
  __shared__ int offs[NPB + 1];
  const int tid = threadIdx.x;
  const int lane = tid & 63;
  const int b = blockIdx.x;
  const int blk = b * NPB;
  const int cnt = bcnt[b];

  if (tid < NPB + 1) offs[tid] = boffs[b * (NPB + 1) + tid];
  const int nI = (cnt + 7) >> 3;
  for (int i = tid; i < cnt; i += 256) srcS[i] = srcsS[(size_t)b * BCAP + i];
  for (int i = cnt + tid; i < nI * 8; i += 256) srcS[i] = ZROW;
  __syncthreads();

  dma_gather(dyn, srcS, offs, cnt, nI, X, Xq, blk, M, As, tid, lane);
  __syncthreads();

  // ---- MFMA: 4 waves 2x2; wave tile 16m x 64n; K=128
  const int w = tid >> 6;
  const int wm = w & 1, wn = w >> 1;
  const int l15 = lane & 15, quad = lane >> 4;
  const int mb = wm * 16, nb2 = wn * 64;

  const unsigned short* bp[4];
#pragma unroll
  for (int nf = 0; nf < 4; ++nf)
    bp[nf] = BT + (size_t)(nb2 + nf * 16 + l15) * 128 + quad * 8;

  v4f acc[4];
#pragma unroll
  for (int nf = 0; nf < 4; ++nf) acc[nf] = (v4f)0.f;

#pragma unroll
  for (int k0 = 0; k0 < 128; k0 += 32) {
    short8 a = *(const short8*)&As[(mb + l15) * 136 + k0 + quad * 8];
    short8 bv[4];
#pragma unroll
    for (int nf = 0; nf < 4; ++nf) bv[nf] = *(const short8*)(bp[nf] + k0);
#pragma unroll
    for (int nf = 0; nf < 4; ++nf)
      acc[nf] = __builtin_amdgcn_mfma_f32_16x16x32_bf16(a, bv[nf], acc[nf], 0, 0, 0);
  }

#pragma unroll
  for (int r = 0; r < 4; ++r) {
    int grow = blk + mb + quad * 4 + r;
    if (grow >= M) continue;
#pragma unroll
    for (int nf = 0; nf < 4; ++nf) {
      int gcol = nb2 + nf * 16 + l15;
      float v = fmaxf(acc[nf][r] + bias[gcol], 0.f);
      C[(size_t)grow * 128 + gcol] = f2bf(v);
      Cq[(size_t)grow * 128 + gcol] = f2fp8(v);
    }
  }
}

// ------------------------- fused layer 3 + MLP head -------------------------
__global__ __launch_bounds__(256) void fused_l3_head(
    const unsigned short* __restrict__ X, const unsigned char* __restrict__ Xq,
    const int* __restrict__ bcnt,
    const int* __restrict__ srcsS, const int* __restrict__ boffs,
    const unsigned short* __restrict__ W2T, const float* __restrict__ b2,
    const unsigned short* __restrict__ Wm1T, const float* __restrict__ bm1,
    const unsigned short* __restrict__ Wm2T, const float* __restrict__ bm2,
    float* __restrict__ out, int M, int NOUT, int ZROW) {
  extern __shared__ __align__(16) char dyn[];   // rows; later aliased by Hs
  __shared__ __align__(16) unsigned short As[NPB * 136];
  __shared__ int srcS[520];
  __shared__ int offs[NPB + 1];
  unsigned short* Hs = (unsigned short*)dyn;    // 32x264 = 16.9KB <= 65KB
  const int tid = threadIdx.x;
  const int lane = tid & 63;
  const int b = blockIdx.x;
  const int blk = b * NPB;
  const int cnt = bcnt[b];

  if (tid < NPB + 1) offs[tid] = boffs[b * (NPB + 1) + tid];
  const int nI = (cnt + 7) >> 3;
  for (int i = tid; i < cnt; i += 256) srcS[i] = srcsS[(size_t)b * BCAP + i];
  for (int i = cnt + tid; i < nI * 8; i += 256) srcS[i] = ZROW;
  __syncthreads();

  dma_gather(dyn, srcS, offs, cnt, nI, X, Xq, blk, M, As, tid, lane);
  __syncthreads();

  // ---- layer-3 MFMA: 32x128, K=128
  const int w = tid >> 6;
  const int wm = w & 1, wn = w >> 1;
  const int l15 = lane & 15, quad = lane >> 4;
  const int mb = wm * 16, nb2 = wn * 64;

  v4f acc[4];
#pragma unroll
  for (int nf = 0; nf < 4; ++nf) acc[nf] = (v4f)0.f;

#pragma unroll
  for (int k0 = 0; k0 < 128; k0 += 32) {
    short8 a = *(const short8*)&As[(mb + l15) * 136 + k0 + quad * 8];
    short8 bv[4];
#pragma unroll
    for (int nf = 0; nf < 4; ++nf)
      bv[nf] = *(const short8*)(W2T + (size_t)(nb2 + nf * 16 + l15) * 128 + quad * 8 + k0);
#pragma unroll
    for (int nf = 0; nf < 4; ++nf)
      acc[nf] = __builtin_amdgcn_mfma_f32_16x16x32_bf16(a, bv[nf], acc[nf], 0, 0, 0);
  }
  __syncthreads();  // all As (and rows) reads done before rewrite

  // t = relu(acc + b2) -> back into As
#pragma unroll
  for (int r = 0; r < 4; ++r) {
    int row = mb + quad * 4 + r;
#pragma unroll
    for (int nf = 0; nf < 4; ++nf) {
      int col = nb2 + nf * 16 + l15;
      As[row * 136 + col] = f2bf(fmaxf(acc[nf][r] + b2[col], 0.f));
    }
  }
  __syncthreads();

  // ---- head phase A: Hm = relu(t @ Wm1 + bm1), 32x256, K=128
  const int nbH = wn * 128;
  v4f acc2[8];
#pragma unroll
  for (int nf = 0; nf < 8; ++nf) acc2[nf] = (v4f)0.f;

#pragma unroll
  for (int k0 = 0; k0 < 128; k0 += 32) {
    short8 a = *(const short8*)&As[(mb + l15) * 136 + k0 + quad * 8];
#pragma unroll
    for (int nf = 0; nf < 8; ++nf) {
      short8 bb = *(const short8*)(Wm1T + (size_t)(nbH + nf * 16 + l15) * 128 + quad * 8 + k0);
      acc2[nf] = __builtin_amdgcn_mfma_f32_16x16x32_bf16(a, bb, acc2[nf], 0, 0, 0);
    }
  }
  __syncthreads();  // As reads done; Hs (aliases dyn) may be written

#pragma unroll
  for (int r = 0; r < 4; ++r) {
    int row = mb + quad * 4 + r;
#pragma unroll
    for (int nf = 0; nf < 8; ++nf) {
      int col = nbH + nf * 16 + l15;
      Hs[row * 264 + col] = f2bf(fmaxf(acc2[nf][r] + bm1[col], 0.f));
    }
  }
  __syncthreads();

  // ---- head phase B: out = Hs @ Wm2 + bm2; 32x16, K=256; waves 0,1 only
  if (w < 2) {
    const int rowl = w * 16 + l15;
    const unsigned short* bp2 = Wm2T + (size_t)l15 * 256 + quad * 8;
    v4f acc3 = (v4f)0.f;
#pragma unroll
    for (int k0 = 0; k0 < 256; k0 += 32)
      acc3 = __builtin_amdgcn_mfma_f32_16x16x32_bf16(
          *(const short8*)&Hs[rowl * 264 + k0 + quad * 8],
          *(const short8*)(bp2 + k0), acc3, 0, 0, 0);
    float bb = (l15 < NOUT) ? bm2[l15] : 0.f;
#pragma unroll
    for (int r = 0; r < 4; ++r) {
      int grow = blk + w * 16 + quad * 4 + r;
      if (grow < M && l15 < NOUT) out[(size_t)grow * NOUT + l15] = acc3[r] + bb;
    }
  }
}

// ---------------------------------------------------------------------------

extern "C" void kernel_launch(void* const* d_in, const int* in_sizes, int n_in,
                              void* d_out, int out_size, void* d_ws, size_t ws_size,
                              hipStream_t stream) {
  const float* x   = (const float*)d_in[0];
  const int*   ei  = (const int*)d_in[1];
  const float* W0  = (const float*)d_in[2];
  const float* b0  = (const float*)d_in[3];
  const float* W1  = (const float*)d_in[4];
  const float* b1  = (const float*)d_in[5];
  const float* W2  = (const float*)d_in[6];
  const float* b2  = (const float*)d_in[7];
  const float* Wm1 = (const float*)d_in[8];
  const float* bm1 = (const float*)d_in[9];
  const float* Wm2 = (const float*)d_in[10];
  const float* bm2 = (const float*)d_in[11];
  float* out = (float*)d_out;

  const int D = 128;
  const int N = in_sizes[0] / D;   // 50000
  const int E = in_sizes[1] / 2;   // 600000
  const int L = in_sizes[11];      // 10
  const int nb = (N + NPB - 1) / NPB;  // 1563 buckets == layer tiles

  const int* srcv = ei;
  const int* dstv = ei + E;

  char* ws = (char*)d_ws;
  size_t off = 0;
  auto alloc = [&](size_t bytes) -> void* {
    void* p = ws + off;
    off = (off + bytes + 255) & ~(size_t)255;
    return p;
  };
  int* bcnt    = (int*)alloc((size_t)MAXB * 4);
  int* bucketA = (int*)alloc((size_t)nb * BCAP * 4);
  int* srcsS   = (int*)alloc((size_t)nb * BCAP * 4);
  int* boffs   = (int*)alloc((size_t)nb * (NPB + 1) * 4);
  unsigned short* xb   = (unsigned short*)alloc((size_t)N * 128 * 2);
  unsigned short* h1   = (unsigned short*)alloc((size_t)N * 128 * 2);
  unsigned short* h2   = (unsigned short*)alloc((size_t)N * 128 * 2);
  unsigned char*  xq   = (unsigned char*)alloc((size_t)(N + 1) * 128);
  unsigned char*  h1q  = (unsigned char*)alloc((size_t)(N + 1) * 128);
  unsigned char*  h2q  = (unsigned char*)alloc((size_t)(N + 1) * 128);
  unsigned short* W0T  = (unsigned short*)alloc(128 * 128 * 2);
  unsigned short* W1T  = (unsigned short*)alloc(128 * 128 * 2);
  unsigned short* W2T  = (unsigned short*)alloc(128 * 128 * 2);
  unsigned short* Wm1T = (unsigned short*)alloc(256 * 128 * 2);
  unsigned short* Wm2T = (unsigned short*)alloc(16 * 256 * 2);
  (void)ws_size; (void)n_in; (void)out_size;

  static bool attr_done = false;
  if (!attr_done) {
    hipFuncSetAttribute(reinterpret_cast<const void*>(fused_layer),
                        hipFuncAttributeMaxDynamicSharedMemorySize, DYN_LDS);
    hipFuncSetAttribute(reinterpret_cast<const void*>(fused_l3_head),
                        hipFuncAttributeMaxDynamicSharedMemorySize, DYN_LDS);
    attr_done = true;
  }

  const int tpb = 256;
  int n8 = N * 16;
  prep_all<<<dim3((n8 + tpb - 1) / tpb), dim3(tpb), 0, stream>>>(
      W0, W1, W2, Wm1, Wm2, W0T, W1T, W2T, Wm1T, Wm2T, x, xb, xq, h1q, h2q, n8, bcnt);

  const int nbin = 256;
  int per = (E + nbin - 1) / nbin;
  bin_edges<<<dim3(nbin), dim3(tpb), 0, stream>>>(srcv, dstv, E, per, bcnt, bucketA, nb);
  sort_buckets<<<dim3(nb), dim3(tpb), 0, stream>>>(bcnt, bucketA, srcsS, boffs);

  dim3 lgrid(nb);
  fused_layer<<<lgrid, dim3(tpb), DYN_LDS, stream>>>(
      xb, xq, bcnt, srcsS, boffs, W0T, b0, h1, h1q, N, N);
  fused_layer<<<lgrid, dim3(tpb), DYN_LDS, stream>>>(
      h1, h1q, bcnt, srcsS, boffs, W1T, b1, h2, h2q, N, N);
  fused_l3_head<<<lgrid, dim3(tpb), DYN_LDS, stream>>>(
      h2, h2q, bcnt, srcsS, boffs, W2T, b2, Wm1T, bm1, Wm2T, bm2, out, N, L, N);
}

// Round 5
// 239.694 us; speedup vs baseline: 1.0525x; 1.0525x over previous
//
#include <hip/hip_runtime.h>

// ---------------------------------------------------------------------------
// GIN: 3 x (bucket gather-sum + (x+agg)@W + b, relu) + MLP head, bf16 MFMA.
// r11: r9 gather restored (dwordx4 fp8, 8 edges/wave-instr = the scattered-
//     instr-wall floor; r10's DMA variant hit the same wall + bank conflicts).
//     New: (1) bf16 hidden arrays h1/h2 dropped -- self term reads fp8 for
//     layers 2/3 (layer-1 self stays bf16 xb); layer epilogue writes fp8
//     only (saves ~38MB streaming traffic). (2) l3 head stages Wm1 (64KB,
//     L1-thrashing) into LDS with 272B-padded rows (2-way bank = free).
//     6 dispatches: prep_all, bin_edges, sort_buckets, 2x fused_layer,
//     fused_l3_head.
// ---------------------------------------------------------------------------

typedef short short8 __attribute__((ext_vector_type(8)));
typedef float v4f __attribute__((ext_vector_type(4)));
typedef float v2f __attribute__((ext_vector_type(2)));

#define BCAP 1024   // bucket capacity: avg 768 edges, +9 sigma head-room
#define MAXB 1024   // >= nbuckets (782)
#define L3_DYN 103424  // Wm1L 69632 + union(As+srcS | Hs) 33792

__device__ inline unsigned short f2bf(float f) {
  union { float f; unsigned int u; } c; c.f = f;
  unsigned int u = c.u;
  return (unsigned short)((u + 0x7fffu + ((u >> 16) & 1u)) >> 16);  // RNE
}
__device__ inline float bfbits2f(unsigned int hi) {
  union { unsigned int u; float f; } c; c.u = hi; return c.f;
}
__device__ inline unsigned int pack2(float a, float b) {
  return (unsigned int)f2bf(a) | ((unsigned int)f2bf(b) << 16);
}
__device__ inline void add8(float* s, uint4 v) {
  s[0] += bfbits2f(v.x << 16); s[1] += bfbits2f(v.x & 0xffff0000u);
  s[2] += bfbits2f(v.y << 16); s[3] += bfbits2f(v.y & 0xffff0000u);
  s[4] += bfbits2f(v.z << 16); s[5] += bfbits2f(v.z & 0xffff0000u);
  s[6] += bfbits2f(v.w << 16); s[7] += bfbits2f(v.w & 0xffff0000u);
}
// decode 16 fp8 (e4m3, HW format) and accumulate into s[0..15]
__device__ inline void addf8q(float* s, uint4 v) {
  v2f p;
  p = __builtin_amdgcn_cvt_pk_f32_fp8(v.x, false); s[0]  += p.x; s[1]  += p.y;
  p = __builtin_amdgcn_cvt_pk_f32_fp8(v.x, true);  s[2]  += p.x; s[3]  += p.y;
  p = __builtin_amdgcn_cvt_pk_f32_fp8(v.y, false); s[4]  += p.x; s[5]  += p.y;
  p = __builtin_amdgcn_cvt_pk_f32_fp8(v.y, true);  s[6]  += p.x; s[7]  += p.y;
  p = __builtin_amdgcn_cvt_pk_f32_fp8(v.z, false); s[8]  += p.x; s[9]  += p.y;
  p = __builtin_amdgcn_cvt_pk_f32_fp8(v.z, true);  s[10] += p.x; s[11] += p.y;
  p = __builtin_amdgcn_cvt_pk_f32_fp8(v.w, false); s[12] += p.x; s[13] += p.y;
  p = __builtin_amdgcn_cvt_pk_f32_fp8(v.w, true);  s[14] += p.x; s[15] += p.y;
}
__device__ inline unsigned char f2fp8(float v) {
  return (unsigned char)(__builtin_amdgcn_cvt_pk_fp8_f32(v, v, 0, false) & 0xff);
}
__device__ inline int wave_incl_scan_int(int v, int lane) {
#pragma unroll
  for (int off = 1; off < 64; off <<= 1) {
    int t = __shfl_up(v, off, 64);
    if (lane >= off) v += t;
  }
  return v;
}

// ------------------------- prep: weights + x->bf16/fp8 + zero bcnt ----------
__global__ __launch_bounds__(256) void prep_all(
    const float* __restrict__ W0, const float* __restrict__ W1, const float* __restrict__ W2,
    const float* __restrict__ Wm1, const float* __restrict__ Wm2,
    unsigned short* __restrict__ W0T, unsigned short* __restrict__ W1T,
    unsigned short* __restrict__ W2T, unsigned short* __restrict__ Wm1T,
    unsigned short* __restrict__ Wm2T,
    const float* __restrict__ x, unsigned short* __restrict__ xb,
    unsigned char* __restrict__ xq, int n8,
    int* __restrict__ bcnt) {
  int i = blockIdx.x * 256 + threadIdx.x;
  if (i < MAXB) bcnt[i] = 0;
  if (i < n8) {
    const float4* p = (const float4*)x;
    float4 a = p[2 * (size_t)i], b = p[2 * (size_t)i + 1];
    uint4 o;
    o.x = pack2(a.x, a.y); o.y = pack2(a.z, a.w);
    o.z = pack2(b.x, b.y); o.w = pack2(b.z, b.w);
    ((uint4*)xb)[i] = o;
    unsigned int lo = 0, hi = 0;
    lo = __builtin_amdgcn_cvt_pk_fp8_f32(a.x, a.y, lo, false);
    lo = __builtin_amdgcn_cvt_pk_fp8_f32(a.z, a.w, lo, true);
    hi = __builtin_amdgcn_cvt_pk_fp8_f32(b.x, b.y, hi, false);
    hi = __builtin_amdgcn_cvt_pk_fp8_f32(b.z, b.w, hi, true);
    uint2 q; q.x = lo; q.y = hi;
    ((uint2*)xq)[i] = q;
  }
  if (i < 49152) {                       // 3 x [128,128] -> [128n][128k]
    int w = i / 16384, r = i % 16384;
    int nn = r >> 7, k = r & 127;
    const float* W = (w == 0) ? W0 : (w == 1) ? W1 : W2;
    unsigned short* O = (w == 0) ? W0T : (w == 1) ? W1T : W2T;
    O[r] = f2bf(W[k * 128 + nn]);
  } else if (i < 49152 + 32768) {        // Wm1 [128,256] -> [256n][128k]
    int r = i - 49152;
    int nn = r >> 7, k = r & 127;
    Wm1T[r] = f2bf(Wm1[k * 256 + nn]);
  } else if (i < 49152 + 32768 + 4096) { // Wm2 [256,10] -> [16n][256k], pad 0
    int r = i - 49152 - 32768;
    int nn = r >> 8, k = r & 255;
    Wm2T[r] = (nn < 10) ? f2bf(Wm2[k * 10 + nn]) : (unsigned short)0;
  }
}

// ------------------------- bin edges into 64-node buckets -------------------
// entry = (src << 6) | (dst & 63); bucket = dst >> 6.
__global__ __launch_bounds__(256) void bin_edges(
    const int* __restrict__ src, const int* __restrict__ dst, int E, int per,
    int* __restrict__ bcnt, int* __restrict__ bucketA, int nbuckets) {
  __shared__ int hist[MAXB];
  __shared__ int base[MAXB];
  const int tid = threadIdx.x;
  const int e0 = blockIdx.x * per;
  const int e1 = (e0 + per < E) ? e0 + per : E;
  for (int j = tid; j < nbuckets; j += 256) hist[j] = 0;
  __syncthreads();
  for (int i = e0 + tid; i < e1; i += 256) atomicAdd(&hist[dst[i] >> 6], 1);
  __syncthreads();
  for (int j = tid; j < nbuckets; j += 256) {
    int h = hist[j];
    base[j] = h ? atomicAdd(&bcnt[j], h) : 0;
  }
  __syncthreads();
  for (int i = e0 + tid; i < e1; i += 256) {
    int d = dst[i], s = src[i];
    int b = d >> 6;
    int r = atomicAdd(&base[b], 1);
    bucketA[(size_t)b * BCAP + r] = (s << 6) | (d & 63);
  }
}

// ------------------------- per-bucket counting sort (once) ------------------
// Produces srcsS[b*BCAP + p] sorted by local node, boffs[b*65 + 0..64].
__global__ __launch_bounds__(256) void sort_buckets(
    const int* __restrict__ bcnt, const int* __restrict__ bucketA,
    int* __restrict__ srcsS, int* __restrict__ boffs) {
  __shared__ int rawE[BCAP];
  __shared__ int hist[64], cur[64], offs[65];
  const int tid = threadIdx.x;
  const int b = blockIdx.x;
  const int cnt = bcnt[b];
  for (int i = tid; i < cnt; i += 256) rawE[i] = bucketA[(size_t)b * BCAP + i];
  if (tid < 64) hist[tid] = 0;
  __syncthreads();
  for (int i = tid; i < cnt; i += 256) atomicAdd(&hist[rawE[i] & 63], 1);
  __syncthreads();
  if (tid < 64) {
    int v = hist[tid];
    int incl = wave_incl_scan_int(v, tid);
    offs[tid] = incl - v;
    cur[tid] = incl - v;
    if (tid == 63) offs[64] = incl;
  }
  __syncthreads();
  for (int i = tid; i < cnt; i += 256) {
    int e = rawE[i];
    int p = atomicAdd(&cur[e & 63], 1);
    srcsS[(size_t)b * BCAP + p] = e >> 6;
  }
  if (tid < 65) boffs[b * 65 + tid] = offs[tid];
}

// ------------------------- fused layer (layers 1,2) -------------------------
// Block = bucket = 64 nodes. Neighbor gather from fp8 Xq via dwordx4: 8
// lanes x 16B per 128B row -> 8 edges per wave instr. Self term: bf16 Xb
// if non-null (layer 1, exact), else fp8 Xq. 2 sweeps x 32 nodes; NO
// barriers in gather. MFMA 64x128 (2x2 waves, 32m x 64n, K=128). fp8 out.
__global__ __launch_bounds__(256) void fused_layer(
    const unsigned short* __restrict__ Xb, const unsigned char* __restrict__ Xq,
    const int* __restrict__ bcnt,
    const int* __restrict__ srcsS, const int* __restrict__ boffs,
    const unsigned short* __restrict__ BT, const float* __restrict__ bias,
    unsigned char* __restrict__ Cq, int M) {
  __shared__ __align__(16) unsigned short As[64 * 136];
  __shared__ int srcS[BCAP];
  __shared__ int offs[65];
  const int tid = threadIdx.x;
  const int lane = tid & 63;
  const int b = blockIdx.x;
  const int blk = b * 64;
  const int cnt = bcnt[b];

  if (tid < 65) offs[tid] = boffs[b * 65 + tid];
  for (int i = tid; i < cnt; i += 256) srcS[i] = srcsS[(size_t)b * BCAP + i];
  __syncthreads();

  // ---- gather: 2 sweeps x 32 nodes; 8 lanes x 16B fp8 per row
  const int l = tid & 7, g = tid >> 3;
  const uint4* baseb = (const uint4*)Xb;  // bf16 rows: 16 x uint4 (may be null)
  const uint4* baseq = (const uint4*)Xq;  // fp8 rows:   8 x uint4
#pragma unroll
  for (int s2 = 0; s2 < 2; ++s2) {
    int nl = s2 * 32 + g;
    int node = blk + nl;
    float s[16] = {0, 0, 0, 0, 0, 0, 0, 0, 0, 0, 0, 0, 0, 0, 0, 0};
    if (node < M) {
      if (Xb) {
        add8(s, baseb[(size_t)node * 16 + l * 2]);
        add8(s + 8, baseb[(size_t)node * 16 + l * 2 + 1]);
      } else {
        addf8q(s, baseq[(size_t)node * 8 + l]);
      }
      int beg = offs[nl], c = offs[nl + 1] - beg;
      int j = 0;
      for (; j + 8 <= c; j += 8) {
        int i0 = srcS[beg + j + 0], i1 = srcS[beg + j + 1];
        int i2 = srcS[beg + j + 2], i3 = srcS[beg + j + 3];
        int i4 = srcS[beg + j + 4], i5 = srcS[beg + j + 5];
        int i6 = srcS[beg + j + 6], i7 = srcS[beg + j + 7];
        uint4 v0 = baseq[(size_t)i0 * 8 + l];
        uint4 v1 = baseq[(size_t)i1 * 8 + l];
        uint4 v2 = baseq[(size_t)i2 * 8 + l];
        uint4 v3 = baseq[(size_t)i3 * 8 + l];
        uint4 v4 = baseq[(size_t)i4 * 8 + l];
        uint4 v5 = baseq[(size_t)i5 * 8 + l];
        uint4 v6 = baseq[(size_t)i6 * 8 + l];
        uint4 v7 = baseq[(size_t)i7 * 8 + l];
        addf8q(s, v0); addf8q(s, v1); addf8q(s, v2); addf8q(s, v3);
        addf8q(s, v4); addf8q(s, v5); addf8q(s, v6); addf8q(s, v7);
      }
      if (j + 4 <= c) {
        int i0 = srcS[beg + j + 0], i1 = srcS[beg + j + 1];
        int i2 = srcS[beg + j + 2], i3 = srcS[beg + j + 3];
        uint4 v0 = baseq[(size_t)i0 * 8 + l];
        uint4 v1 = baseq[(size_t)i1 * 8 + l];
        uint4 v2 = baseq[(size_t)i2 * 8 + l];
        uint4 v3 = baseq[(size_t)i3 * 8 + l];
        addf8q(s, v0); addf8q(s, v1); addf8q(s, v2); addf8q(s, v3);
        j += 4;
      }
      if (j + 2 <= c) {
        int i0 = srcS[beg + j + 0], i1 = srcS[beg + j + 1];
        uint4 v0 = baseq[(size_t)i0 * 8 + l];
        uint4 v1 = baseq[(size_t)i1 * 8 + l];
        addf8q(s, v0); addf8q(s, v1);
        j += 2;
      }
      if (j < c) addf8q(s, baseq[(size_t)srcS[beg + j] * 8 + l]);
    }
    uint4 o0, o1;
    o0.x = pack2(s[0], s[1]);   o0.y = pack2(s[2], s[3]);
    o0.z = pack2(s[4], s[5]);   o0.w = pack2(s[6], s[7]);
    o1.x = pack2(s[8], s[9]);   o1.y = pack2(s[10], s[11]);
    o1.z = pack2(s[12], s[13]); o1.w = pack2(s[14], s[15]);
    *(uint4*)&As[nl * 136 + l * 16] = o0;
    *(uint4*)&As[nl * 136 + l * 16 + 8] = o1;
  }
  __syncthreads();

  // ---- MFMA: 4 waves 2x2; wave tile 32m x 64n; K=128
  const int w = tid >> 6;
  const int wm = w & 1, wn = w >> 1;
  const int l15 = lane & 15, quad = lane >> 4;
  const int mb = wm * 32, nb2 = wn * 64;

  const unsigned short* bp[4];
#pragma unroll
  for (int nf = 0; nf < 4; ++nf)
    bp[nf] = BT + (size_t)(nb2 + nf * 16 + l15) * 128 + quad * 8;

  v4f acc[2][4];
#pragma unroll
  for (int mf = 0; mf < 2; ++mf)
#pragma unroll
    for (int nf = 0; nf < 4; ++nf) acc[mf][nf] = (v4f)0.f;

#pragma unroll
  for (int k0 = 0; k0 < 128; k0 += 32) {
    short8 a[2], bv[4];
#pragma unroll
    for (int mf = 0; mf < 2; ++mf)
      a[mf] = *(const short8*)&As[(mb + mf * 16 + l15) * 136 + k0 + quad * 8];
#pragma unroll
    for (int nf = 0; nf < 4; ++nf) bv[nf] = *(const short8*)(bp[nf] + k0);
#pragma unroll
    for (int mf = 0; mf < 2; ++mf)
#pragma unroll
      for (int nf = 0; nf < 4; ++nf)
        acc[mf][nf] = __builtin_amdgcn_mfma_f32_16x16x32_bf16(a[mf], bv[nf], acc[mf][nf], 0, 0, 0);
  }

#pragma unroll
  for (int mf = 0; mf < 2; ++mf) {
#pragma unroll
    for (int r = 0; r < 4; ++r) {
      int grow = blk + mb + mf * 16 + quad * 4 + r;
      if (grow >= M) continue;
#pragma unroll
      for (int nf = 0; nf < 4; ++nf) {
        int gcol = nb2 + nf * 16 + l15;
        float v = fmaxf(acc[mf][nf][r] + bias[gcol], 0.f);
        Cq[(size_t)grow * 128 + gcol] = f2fp8(v);
      }
    }
  }
}

// ------------------------- fused layer 3 + MLP head -------------------------
// Gather (self from fp8) + layer-3 MFMA, then head in LDS. Wm1 (64KB,
// L1-thrashing) is staged into LDS with 272B-padded rows (2-way bank).
//   dyn: [Wm1L 69632B][U 33792B: (As 17408 + srcS 4096) then Hs]
__global__ __launch_bounds__(256) void fused_l3_head(
    const unsigned char* __restrict__ Xq,
    const int* __restrict__ bcnt,
    const int* __restrict__ srcsS, const int* __restrict__ boffs,
    const unsigned short* __restrict__ W2T, const float* __restrict__ b2,
    const unsigned short* __restrict__ Wm1T, const float* __restrict__ bm1,
    const unsigned short* __restrict__ Wm2T, const float* __restrict__ bm2,
    float* __restrict__ out, int M, int NOUT) {
  extern __shared__ __align__(16) char dyn[];
  unsigned short* Wm1L = (unsigned short*)dyn;            // 256 x 136 sh
  char* U = dyn + 69632;
  unsigned short* As = (unsigned short*)U;                // 64 x 136 sh
  int* srcS = (int*)(U + 64 * 136 * 2);                   // 1024 ints
  unsigned short* Hs = (unsigned short*)U;                // 64 x 264 sh
  __shared__ int offs[65];
  const int tid = threadIdx.x;
  const int lane = tid & 63;
  const int b = blockIdx.x;
  const int blk = b * 64;
  const int cnt = bcnt[b];

  if (tid < 65) offs[tid] = boffs[b * 65 + tid];
  for (int i = tid; i < cnt; i += 256) srcS[i] = srcsS[(size_t)b * BCAP + i];
  // stage Wm1T -> Wm1L (coalesced 16B chunks; padded 136-short rows)
  for (int c = tid; c < 4096; c += 256) {
    int row = c >> 4, ch = c & 15;
    *(uint4*)&Wm1L[row * 136 + ch * 8] = *(const uint4*)&Wm1T[row * 128 + ch * 8];
  }
  __syncthreads();

  // ---- gather (self from fp8 Xq)
  const int l = tid & 7, g = tid >> 3;
  const uint4* baseq = (const uint4*)Xq;
#pragma unroll
  for (int s2 = 0; s2 < 2; ++s2) {
    int nl = s2 * 32 + g;
    int node = blk + nl;
    float s[16] = {0, 0, 0, 0, 0, 0, 0, 0, 0, 0, 0, 0, 0, 0, 0, 0};
    if (node < M) {
      addf8q(s, baseq[(size_t)node * 8 + l]);
      int beg = offs[nl], c = offs[nl + 1] - beg;
      int j = 0;
      for (; j + 8 <= c; j += 8) {
        int i0 = srcS[beg + j + 0], i1 = srcS[beg + j + 1];
        int i2 = srcS[beg + j + 2], i3 = srcS[beg + j + 3];
        int i4 = srcS[beg + j + 4], i5 = srcS[beg + j + 5];
        int i6 = srcS[beg + j + 6], i7 = srcS[beg + j + 7];
        uint4 v0 = baseq[(size_t)i0 * 8 + l];
        uint4 v1 = baseq[(size_t)i1 * 8 + l];
        uint4 v2 = baseq[(size_t)i2 * 8 + l];
        uint4 v3 = baseq[(size_t)i3 * 8 + l];
        uint4 v4 = baseq[(size_t)i4 * 8 + l];
        uint4 v5 = baseq[(size_t)i5 * 8 + l];
        uint4 v6 = baseq[(size_t)i6 * 8 + l];
        uint4 v7 = baseq[(size_t)i7 * 8 + l];
        addf8q(s, v0); addf8q(s, v1); addf8q(s, v2); addf8q(s, v3);
        addf8q(s, v4); addf8q(s, v5); addf8q(s, v6); addf8q(s, v7);
      }
      if (j + 4 <= c) {
        int i0 = srcS[beg + j + 0], i1 = srcS[beg + j + 1];
        int i2 = srcS[beg + j + 2], i3 = srcS[beg + j + 3];
        uint4 v0 = baseq[(size_t)i0 * 8 + l];
        uint4 v1 = baseq[(size_t)i1 * 8 + l];
        uint4 v2 = baseq[(size_t)i2 * 8 + l];
        uint4 v3 = baseq[(size_t)i3 * 8 + l];
        addf8q(s, v0); addf8q(s, v1); addf8q(s, v2); addf8q(s, v3);
        j += 4;
      }
      if (j + 2 <= c) {
        int i0 = srcS[beg + j + 0], i1 = srcS[beg + j + 1];
        uint4 v0 = baseq[(size_t)i0 * 8 + l];
        uint4 v1 = baseq[(size_t)i1 * 8 + l];
        addf8q(s, v0); addf8q(s, v1);
        j += 2;
      }
      if (j < c) addf8q(s, baseq[(size_t)srcS[beg + j] * 8 + l]);
    }
    uint4 o0, o1;
    o0.x = pack2(s[0], s[1]);   o0.y = pack2(s[2], s[3]);
    o0.z = pack2(s[4], s[5]);   o0.w = pack2(s[6], s[7]);
    o1.x = pack2(s[8], s[9]);   o1.y = pack2(s[10], s[11]);
    o1.z = pack2(s[12], s[13]); o1.w = pack2(s[14], s[15]);
    *(uint4*)&As[nl * 136 + l * 16] = o0;
    *(uint4*)&As[nl * 136 + l * 16 + 8] = o1;
  }
  __syncthreads();

  // ---- layer-3 MFMA: 64x128, K=128 (W2T from global; 32KB ~ L1-resident)
  const int w = tid >> 6;
  const int wm = w & 1, wn = w >> 1;
  const int l15 = lane & 15, quad = lane >> 4;
  const int mb = wm * 32, nb2 = wn * 64;

  v4f acc[2][4];
#pragma unroll
  for (int mf = 0; mf < 2; ++mf)
#pragma unroll
    for (int nf = 0; nf < 4; ++nf) acc[mf][nf] = (v4f)0.f;

#pragma unroll
  for (int k0 = 0; k0 < 128; k0 += 32) {
    short8 a[2], bv[4];
#pragma unroll
    for (int mf = 0; mf < 2; ++mf)
      a[mf] = *(const short8*)&As[(mb + mf * 16 + l15) * 136 + k0 + quad * 8];
#pragma unroll
    for (int nf = 0; nf < 4; ++nf)
      bv[nf] = *(const short8*)(W2T + (size_t)(nb2 + nf * 16 + l15) * 128 + quad * 8 + k0);
#pragma unroll
    for (int mf = 0; mf < 2; ++mf)
#pragma unroll
      for (int nf = 0; nf < 4; ++nf)
        acc[mf][nf] = __builtin_amdgcn_mfma_f32_16x16x32_bf16(a[mf], bv[nf], acc[mf][nf], 0, 0, 0);
  }
  __syncthreads();  // all As reads done before rewrite

  // t = relu(acc + b2) -> back into As (local rows 0..63, cols 0..127)
#pragma unroll
  for (int mf = 0; mf < 2; ++mf)
#pragma unroll
    for (int r = 0; r < 4; ++r) {
      int row = mb + mf * 16 + quad * 4 + r;
#pragma unroll
      for (int nf = 0; nf < 4; ++nf) {
        int col = nb2 + nf * 16 + l15;
        As[row * 136 + col] = f2bf(fmaxf(acc[mf][nf][r] + b2[col], 0.f));
      }
    }
  __syncthreads();

  // ---- head phase A: Hm = relu(t @ Wm1 + bm1), 64x256, K=128; Wm1 in LDS
  const int nbH = wn * 128;
  v4f acc2[2][8];
#pragma unroll
  for (int mf = 0; mf < 2; ++mf)
#pragma unroll
    for (int nf = 0; nf < 8; ++nf) acc2[mf][nf] = (v4f)0.f;

#pragma unroll
  for (int k0 = 0; k0 < 128; k0 += 32) {
    short8 a[2];
#pragma unroll
    for (int mf = 0; mf < 2; ++mf)
      a[mf] = *(const short8*)&As[(mb + mf * 16 + l15) * 136 + k0 + quad * 8];
#pragma unroll
    for (int nf = 0; nf < 8; ++nf) {
      short8 bb = *(const short8*)&Wm1L[(nbH + nf * 16 + l15) * 136 + quad * 8 + k0];
#pragma unroll
      for (int mf = 0; mf < 2; ++mf)
        acc2[mf][nf] = __builtin_amdgcn_mfma_f32_16x16x32_bf16(a[mf], bb, acc2[mf][nf], 0, 0, 0);
    }
  }
  __syncthreads();  // As reads done; Hs may overwrite

#pragma unroll
  for (int mf = 0; mf < 2; ++mf)
#pragma unroll
    for (int r = 0; r < 4; ++r) {
      int row = mb + mf * 16 + quad * 4 + r;
#pragma unroll
      for (int nf = 0; nf < 8; ++nf) {
        int col = nbH + nf * 16 + l15;
        Hs[row * 264 + col] = f2bf(fmaxf(acc2[mf][nf][r] + bm1[col], 0.f));
      }
    }
  __syncthreads();

  // ---- head phase B: out = Hs @ Wm2 + bm2; 64x16, K=256; wave = 16 rows
  const int rowl = w * 16 + l15;
  const unsigned short* bp2 = Wm2T + (size_t)l15 * 256 + quad * 8;
  v4f acc3 = (v4f)0.f;
#pragma unroll
  for (int k0 = 0; k0 < 256; k0 += 32)
    acc3 = __builtin_amdgcn_mfma_f32_16x16x32_bf16(
        *(const short8*)&Hs[rowl * 264 + k0 + quad * 8],
        *(const short8*)(bp2 + k0), acc3, 0, 0, 0);
  float bb = (l15 < NOUT) ? bm2[l15] : 0.f;
#pragma unroll
  for (int r = 0; r < 4; ++r) {
    int grow = blk + w * 16 + quad * 4 + r;
    if (grow < M && l15 < NOUT) out[(size_t)grow * NOUT + l15] = acc3[r] + bb;
  }
}

// ---------------------------------------------------------------------------

extern "C" void kernel_launch(void* const* d_in, const int* in_sizes, int n_in,
                              void* d_out, int out_size, void* d_ws, size_t ws_size,
                              hipStream_t stream) {
  const float* x   = (const float*)d_in[0];
  const int*   ei  = (const int*)d_in[1];
  const float* W0  = (const float*)d_in[2];
  const float* b0  = (const float*)d_in[3];
  const float* W1  = (const float*)d_in[4];
  const float* b1  = (const float*)d_in[5];
  const float* W2  = (const float*)d_in[6];
  const float* b2  = (const float*)d_in[7];
  const float* Wm1 = (const float*)d_in[8];
  const float* bm1 = (const float*)d_in[9];
  const float* Wm2 = (const float*)d_in[10];
  const float* bm2 = (const float*)d_in[11];
  float* out = (float*)d_out;

  const int D = 128;
  const int N = in_sizes[0] / D;   // 50000
  const int E = in_sizes[1] / 2;   // 600000
  const int L = in_sizes[11];      // 10
  const int nb = (N + 63) / 64;    // 782 buckets == layer tiles

  const int* srcv = ei;
  const int* dstv = ei + E;

  char* ws = (char*)d_ws;
  size_t off = 0;
  auto alloc = [&](size_t bytes) -> void* {
    void* p = ws + off;
    off = (off + bytes + 255) & ~(size_t)255;
    return p;
  };
  int* bcnt    = (int*)alloc((size_t)MAXB * 4);
  int* bucketA = (int*)alloc((size_t)nb * BCAP * 4);
  int* srcsS   = (int*)alloc((size_t)nb * BCAP * 4);
  int* boffs   = (int*)alloc((size_t)nb * 65 * 4);
  unsigned short* xb   = (unsigned short*)alloc((size_t)N * 128 * 2);
  unsigned char*  xq   = (unsigned char*)alloc((size_t)N * 128);
  unsigned char*  h1q  = (unsigned char*)alloc((size_t)N * 128);
  unsigned char*  h2q  = (unsigned char*)alloc((size_t)N * 128);
  unsigned short* W0T  = (unsigned short*)alloc(128 * 128 * 2);
  unsigned short* W1T  = (unsigned short*)alloc(128 * 128 * 2);
  unsigned short* W2T  = (unsigned short*)alloc(128 * 128 * 2);
  unsigned short* Wm1T = (unsigned short*)alloc(256 * 128 * 2);
  unsigned short* Wm2T = (unsigned short*)alloc(16 * 256 * 2);
  (void)ws_size; (void)n_in; (void)out_size;

  static bool attr_done = false;
  if (!attr_done) {
    hipFuncSetAttribute(reinterpret_cast<const void*>(fused_l3_head),
                        hipFuncAttributeMaxDynamicSharedMemorySize, L3_DYN);
    attr_done = true;
  }

  const int tpb = 256;
  int n8 = N * 16;
  prep_all<<<dim3((n8 + tpb - 1) / tpb), dim3(tpb), 0, stream>>>(
      W0, W1, W2, Wm1, Wm2, W0T, W1T, W2T, Wm1T, Wm2T, x, xb, xq, n8, bcnt);

  const int nbin = 256;
  int per = (E + nbin - 1) / nbin;
  bin_edges<<<dim3(nbin), dim3(tpb), 0, stream>>>(srcv, dstv, E, per, bcnt, bucketA, nb);
  sort_buckets<<<dim3(nb), dim3(tpb), 0, stream>>>(bcnt, bucketA, srcsS, boffs);

  dim3 lgrid(nb);
  fused_layer<<<lgrid, dim3(tpb), 0, stream>>>(
      xb, xq, bcnt, srcsS, boffs, W0T, b0, h1q, N);          // L1: self bf16
  fused_layer<<<lgrid, dim3(tpb), 0, stream>>>(
      nullptr, h1q, bcnt, srcsS, boffs, W1T, b1, h2q, N);    // L2: self fp8
  fused_l3_head<<<lgrid, dim3(tpb), L3_DYN, stream>>>(
      h2q, bcnt, srcsS, boffs, W2T, b2, Wm1T, bm1, Wm2T, bm2, out, N, L);
}

// Round 6
// 220.150 us; speedup vs baseline: 1.1459x; 1.0888x over previous
//
#include <hip/hip_runtime.h>

// ---------------------------------------------------------------------------
// GIN: 3 x (bucket gather-sum + (x+agg)@W + b, relu) + MLP head, bf16 MFMA.
// r12: r11 minus the Wm1-LDS-staging occupancy cliff (103KB LDS -> 1 blk/CU,
//     l3 50->86us). l3_head back to r9's static-34KB-LDS structure (>=3-4
//     blk/CU) with Wm1T from global (L2-resident; head MFMA not critical),
//     keeping r11's wins: fp8-only hidden state (h1q/h2q, no bf16 h arrays)
//     and fp8 self term for layers 2/3 (layer-1 self stays exact bf16 xb).
//     Gather law (r6-r10): time = scattered-instrs x ~188cyc/CU flat;
//     r9 dwordx4-fp8 (8 edges/instr) is the fp8 floor -- unchanged here.
//     6 dispatches: prep_all, bin_edges, sort_buckets, 2x fused_layer,
//     fused_l3_head.
// ---------------------------------------------------------------------------

typedef short short8 __attribute__((ext_vector_type(8)));
typedef float v4f __attribute__((ext_vector_type(4)));
typedef float v2f __attribute__((ext_vector_type(2)));

#define BCAP 1024   // bucket capacity: avg 768 edges, +9 sigma head-room
#define MAXB 1024   // >= nbuckets (782)

__device__ inline unsigned short f2bf(float f) {
  union { float f; unsigned int u; } c; c.f = f;
  unsigned int u = c.u;
  return (unsigned short)((u + 0x7fffu + ((u >> 16) & 1u)) >> 16);  // RNE
}
__device__ inline float bfbits2f(unsigned int hi) {
  union { unsigned int u; float f; } c; c.u = hi; return c.f;
}
__device__ inline unsigned int pack2(float a, float b) {
  return (unsigned int)f2bf(a) | ((unsigned int)f2bf(b) << 16);
}
__device__ inline void add8(float* s, uint4 v) {
  s[0] += bfbits2f(v.x << 16); s[1] += bfbits2f(v.x & 0xffff0000u);
  s[2] += bfbits2f(v.y << 16); s[3] += bfbits2f(v.y & 0xffff0000u);
  s[4] += bfbits2f(v.z << 16); s[5] += bfbits2f(v.z & 0xffff0000u);
  s[6] += bfbits2f(v.w << 16); s[7] += bfbits2f(v.w & 0xffff0000u);
}
// decode 16 fp8 (e4m3, HW format) and accumulate into s[0..15]
__device__ inline void addf8q(float* s, uint4 v) {
  v2f p;
  p = __builtin_amdgcn_cvt_pk_f32_fp8(v.x, false); s[0]  += p.x; s[1]  += p.y;
  p = __builtin_amdgcn_cvt_pk_f32_fp8(v.x, true);  s[2]  += p.x; s[3]  += p.y;
  p = __builtin_amdgcn_cvt_pk_f32_fp8(v.y, false); s[4]  += p.x; s[5]  += p.y;
  p = __builtin_amdgcn_cvt_pk_f32_fp8(v.y, true);  s[6]  += p.x; s[7]  += p.y;
  p = __builtin_amdgcn_cvt_pk_f32_fp8(v.z, false); s[8]  += p.x; s[9]  += p.y;
  p = __builtin_amdgcn_cvt_pk_f32_fp8(v.z, true);  s[10] += p.x; s[11] += p.y;
  p = __builtin_amdgcn_cvt_pk_f32_fp8(v.w, false); s[12] += p.x; s[13] += p.y;
  p = __builtin_amdgcn_cvt_pk_f32_fp8(v.w, true);  s[14] += p.x; s[15] += p.y;
}
__device__ inline unsigned char f2fp8(float v) {
  return (unsigned char)(__builtin_amdgcn_cvt_pk_fp8_f32(v, v, 0, false) & 0xff);
}
__device__ inline int wave_incl_scan_int(int v, int lane) {
#pragma unroll
  for (int off = 1; off < 64; off <<= 1) {
    int t = __shfl_up(v, off, 64);
    if (lane >= off) v += t;
  }
  return v;
}

// ------------------------- prep: weights + x->bf16/fp8 + zero bcnt ----------
__global__ __launch_bounds__(256) void prep_all(
    const float* __restrict__ W0, const float* __restrict__ W1, const float* __restrict__ W2,
    const float* __restrict__ Wm1, const float* __restrict__ Wm2,
    unsigned short* __restrict__ W0T, unsigned short* __restrict__ W1T,
    unsigned short* __restrict__ W2T, unsigned short* __restrict__ Wm1T,
    unsigned short* __restrict__ Wm2T,
    const float* __restrict__ x, unsigned short* __restrict__ xb,
    unsigned char* __restrict__ xq, int n8,
    int* __restrict__ bcnt) {
  int i = blockIdx.x * 256 + threadIdx.x;
  if (i < MAXB) bcnt[i] = 0;
  if (i < n8) {
    const float4* p = (const float4*)x;
    float4 a = p[2 * (size_t)i], b = p[2 * (size_t)i + 1];
    uint4 o;
    o.x = pack2(a.x, a.y); o.y = pack2(a.z, a.w);
    o.z = pack2(b.x, b.y); o.w = pack2(b.z, b.w);
    ((uint4*)xb)[i] = o;
    unsigned int lo = 0, hi = 0;
    lo = __builtin_amdgcn_cvt_pk_fp8_f32(a.x, a.y, lo, false);
    lo = __builtin_amdgcn_cvt_pk_fp8_f32(a.z, a.w, lo, true);
    hi = __builtin_amdgcn_cvt_pk_fp8_f32(b.x, b.y, hi, false);
    hi = __builtin_amdgcn_cvt_pk_fp8_f32(b.z, b.w, hi, true);
    uint2 q; q.x = lo; q.y = hi;
    ((uint2*)xq)[i] = q;
  }
  if (i < 49152) {                       // 3 x [128,128] -> [128n][128k]
    int w = i / 16384, r = i % 16384;
    int nn = r >> 7, k = r & 127;
    const float* W = (w == 0) ? W0 : (w == 1) ? W1 : W2;
    unsigned short* O = (w == 0) ? W0T : (w == 1) ? W1T : W2T;
    O[r] = f2bf(W[k * 128 + nn]);
  } else if (i < 49152 + 32768) {        // Wm1 [128,256] -> [256n][128k]
    int r = i - 49152;
    int nn = r >> 7, k = r & 127;
    Wm1T[r] = f2bf(Wm1[k * 256 + nn]);
  } else if (i < 49152 + 32768 + 4096) { // Wm2 [256,10] -> [16n][256k], pad 0
    int r = i - 49152 - 32768;
    int nn = r >> 8, k = r & 255;
    Wm2T[r] = (nn < 10) ? f2bf(Wm2[k * 10 + nn]) : (unsigned short)0;
  }
}

// ------------------------- bin edges into 64-node buckets -------------------
// entry = (src << 6) | (dst & 63); bucket = dst >> 6.
__global__ __launch_bounds__(256) void bin_edges(
    const int* __restrict__ src, const int* __restrict__ dst, int E, int per,
    int* __restrict__ bcnt, int* __restrict__ bucketA, int nbuckets) {
  __shared__ int hist[MAXB];
  __shared__ int base[MAXB];
  const int tid = threadIdx.x;
  const int e0 = blockIdx.x * per;
  const int e1 = (e0 + per < E) ? e0 + per : E;
  for (int j = tid; j < nbuckets; j += 256) hist[j] = 0;
  __syncthreads();
  for (int i = e0 + tid; i < e1; i += 256) atomicAdd(&hist[dst[i] >> 6], 1);
  __syncthreads();
  for (int j = tid; j < nbuckets; j += 256) {
    int h = hist[j];
    base[j] = h ? atomicAdd(&bcnt[j], h) : 0;
  }
  __syncthreads();
  for (int i = e0 + tid; i < e1; i += 256) {
    int d = dst[i], s = src[i];
    int b = d >> 6;
    int r = atomicAdd(&base[b], 1);
    bucketA[(size_t)b * BCAP + r] = (s << 6) | (d & 63);
  }
}

// ------------------------- per-bucket counting sort (once) ------------------
// Produces srcsS[b*BCAP + p] sorted by local node, boffs[b*65 + 0..64].
__global__ __launch_bounds__(256) void sort_buckets(
    const int* __restrict__ bcnt, const int* __restrict__ bucketA,
    int* __restrict__ srcsS, int* __restrict__ boffs) {
  __shared__ int rawE[BCAP];
  __shared__ int hist[64], cur[64], offs[65];
  const int tid = threadIdx.x;
  const int b = blockIdx.x;
  const int cnt = bcnt[b];
  for (int i = tid; i < cnt; i += 256) rawE[i] = bucketA[(size_t)b * BCAP + i];
  if (tid < 64) hist[tid] = 0;
  __syncthreads();
  for (int i = tid; i < cnt; i += 256) atomicAdd(&hist[rawE[i] & 63], 1);
  __syncthreads();
  if (tid < 64) {
    int v = hist[tid];
    int incl = wave_incl_scan_int(v, tid);
    offs[tid] = incl - v;
    cur[tid] = incl - v;
    if (tid == 63) offs[64] = incl;
  }
  __syncthreads();
  for (int i = tid; i < cnt; i += 256) {
    int e = rawE[i];
    int p = atomicAdd(&cur[e & 63], 1);
    srcsS[(size_t)b * BCAP + p] = e >> 6;
  }
  if (tid < 65) boffs[b * 65 + tid] = offs[tid];
}

// ------------------------- fused layer (layers 1,2) -------------------------
// Block = bucket = 64 nodes. Neighbor gather from fp8 Xq via dwordx4: 8
// lanes x 16B per 128B row -> 8 edges per wave instr. Self term: bf16 Xb
// if non-null (layer 1, exact), else fp8 Xq. 2 sweeps x 32 nodes; NO
// barriers in gather. MFMA 64x128 (2x2 waves, 32m x 64n, K=128). fp8 out.
__global__ __launch_bounds__(256) void fused_layer(
    const unsigned short* __restrict__ Xb, const unsigned char* __restrict__ Xq,
    const int* __restrict__ bcnt,
    const int* __restrict__ srcsS, const int* __restrict__ boffs,
    const unsigned short* __restrict__ BT, const float* __restrict__ bias,
    unsigned char* __restrict__ Cq, int M) {
  __shared__ __align__(16) unsigned short As[64 * 136];
  __shared__ int srcS[BCAP];
  __shared__ int offs[65];
  const int tid = threadIdx.x;
  const int lane = tid & 63;
  const int b = blockIdx.x;
  const int blk = b * 64;
  const int cnt = bcnt[b];

  if (tid < 65) offs[tid] = boffs[b * 65 + tid];
  for (int i = tid; i < cnt; i += 256) srcS[i] = srcsS[(size_t)b * BCAP + i];
  __syncthreads();

  // ---- gather: 2 sweeps x 32 nodes; 8 lanes x 16B fp8 per row
  const int l = tid & 7, g = tid >> 3;
  const uint4* baseb = (const uint4*)Xb;  // bf16 rows: 16 x uint4 (may be null)
  const uint4* baseq = (const uint4*)Xq;  // fp8 rows:   8 x uint4
#pragma unroll
  for (int s2 = 0; s2 < 2; ++s2) {
    int nl = s2 * 32 + g;
    int node = blk + nl;
    float s[16] = {0, 0, 0, 0, 0, 0, 0, 0, 0, 0, 0, 0, 0, 0, 0, 0};
    if (node < M) {
      if (Xb) {
        add8(s, baseb[(size_t)node * 16 + l * 2]);
        add8(s + 8, baseb[(size_t)node * 16 + l * 2 + 1]);
      } else {
        addf8q(s, baseq[(size_t)node * 8 + l]);
      }
      int beg = offs[nl], c = offs[nl + 1] - beg;
      int j = 0;
      for (; j + 8 <= c; j += 8) {
        int i0 = srcS[beg + j + 0], i1 = srcS[beg + j + 1];
        int i2 = srcS[beg + j + 2], i3 = srcS[beg + j + 3];
        int i4 = srcS[beg + j + 4], i5 = srcS[beg + j + 5];
        int i6 = srcS[beg + j + 6], i7 = srcS[beg + j + 7];
        uint4 v0 = baseq[(size_t)i0 * 8 + l];
        uint4 v1 = baseq[(size_t)i1 * 8 + l];
        uint4 v2 = baseq[(size_t)i2 * 8 + l];
        uint4 v3 = baseq[(size_t)i3 * 8 + l];
        uint4 v4 = baseq[(size_t)i4 * 8 + l];
        uint4 v5 = baseq[(size_t)i5 * 8 + l];
        uint4 v6 = baseq[(size_t)i6 * 8 + l];
        uint4 v7 = baseq[(size_t)i7 * 8 + l];
        addf8q(s, v0); addf8q(s, v1); addf8q(s, v2); addf8q(s, v3);
        addf8q(s, v4); addf8q(s, v5); addf8q(s, v6); addf8q(s, v7);
      }
      if (j + 4 <= c) {
        int i0 = srcS[beg + j + 0], i1 = srcS[beg + j + 1];
        int i2 = srcS[beg + j + 2], i3 = srcS[beg + j + 3];
        uint4 v0 = baseq[(size_t)i0 * 8 + l];
        uint4 v1 = baseq[(size_t)i1 * 8 + l];
        uint4 v2 = baseq[(size_t)i2 * 8 + l];
        uint4 v3 = baseq[(size_t)i3 * 8 + l];
        addf8q(s, v0); addf8q(s, v1); addf8q(s, v2); addf8q(s, v3);
        j += 4;
      }
      if (j + 2 <= c) {
        int i0 = srcS[beg + j + 0], i1 = srcS[beg + j + 1];
        uint4 v0 = baseq[(size_t)i0 * 8 + l];
        uint4 v1 = baseq[(size_t)i1 * 8 + l];
        addf8q(s, v0); addf8q(s, v1);
        j += 2;
      }
      if (j < c) addf8q(s, baseq[(size_t)srcS[beg + j] * 8 + l]);
    }
    uint4 o0, o1;
    o0.x = pack2(s[0], s[1]);   o0.y = pack2(s[2], s[3]);
    o0.z = pack2(s[4], s[5]);   o0.w = pack2(s[6], s[7]);
    o1.x = pack2(s[8], s[9]);   o1.y = pack2(s[10], s[11]);
    o1.z = pack2(s[12], s[13]); o1.w = pack2(s[14], s[15]);
    *(uint4*)&As[nl * 136 + l * 16] = o0;
    *(uint4*)&As[nl * 136 + l * 16 + 8] = o1;
  }
  __syncthreads();

  // ---- MFMA: 4 waves 2x2; wave tile 32m x 64n; K=128
  const int w = tid >> 6;
  const int wm = w & 1, wn = w >> 1;
  const int l15 = lane & 15, quad = lane >> 4;
  const int mb = wm * 32, nb2 = wn * 64;

  const unsigned short* bp[4];
#pragma unroll
  for (int nf = 0; nf < 4; ++nf)
    bp[nf] = BT + (size_t)(nb2 + nf * 16 + l15) * 128 + quad * 8;

  v4f acc[2][4];
#pragma unroll
  for (int mf = 0; mf < 2; ++mf)
#pragma unroll
    for (int nf = 0; nf < 4; ++nf) acc[mf][nf] = (v4f)0.f;

#pragma unroll
  for (int k0 = 0; k0 < 128; k0 += 32) {
    short8 a[2], bv[4];
#pragma unroll
    for (int mf = 0; mf < 2; ++mf)
      a[mf] = *(const short8*)&As[(mb + mf * 16 + l15) * 136 + k0 + quad * 8];
#pragma unroll
    for (int nf = 0; nf < 4; ++nf) bv[nf] = *(const short8*)(bp[nf] + k0);
#pragma unroll
    for (int mf = 0; mf < 2; ++mf)
#pragma unroll
      for (int nf = 0; nf < 4; ++nf)
        acc[mf][nf] = __builtin_amdgcn_mfma_f32_16x16x32_bf16(a[mf], bv[nf], acc[mf][nf], 0, 0, 0);
  }

#pragma unroll
  for (int mf = 0; mf < 2; ++mf) {
#pragma unroll
    for (int r = 0; r < 4; ++r) {
      int grow = blk + mb + mf * 16 + quad * 4 + r;
      if (grow >= M) continue;
#pragma unroll
      for (int nf = 0; nf < 4; ++nf) {
        int gcol = nb2 + nf * 16 + l15;
        float v = fmaxf(acc[mf][nf][r] + bias[gcol], 0.f);
        Cq[(size_t)grow * 128 + gcol] = f2fp8(v);
      }
    }
  }
}

// ------------------------- fused layer 3 + MLP head -------------------------
// fp8-self gather + layer-3 MFMA, then head in LDS (r9 layout, 34KB union):
//   t  = relu((x+agg)@W2 + b2)      -> back into As
//   Hs = relu(t @ Wm1 + bm1)        -> Hs (aliases As+srcS)
//   out= Hs @ Wm2 + bm2             (Wm2T zero-padded to 16 cols)
__global__ __launch_bounds__(256) void fused_l3_head(
    const unsigned char* __restrict__ Xq,
    const int* __restrict__ bcnt,
    const int* __restrict__ srcsS, const int* __restrict__ boffs,
    const unsigned short* __restrict__ W2T, const float* __restrict__ b2,
    const unsigned short* __restrict__ Wm1T, const float* __restrict__ bm1,
    const unsigned short* __restrict__ Wm2T, const float* __restrict__ bm2,
    float* __restrict__ out, int M, int NOUT) {
  __shared__ __align__(16) unsigned char lds[64 * 264 * 2];  // Hs 33.8KB
  unsigned short* As = (unsigned short*)lds;                 // 17.4KB
  int* srcS = (int*)(lds + 64 * 136 * 2);                    // 4KB after As
  unsigned short* Hs = (unsigned short*)lds;                 // aliases both
  __shared__ int offs[65];
  const int tid = threadIdx.x;
  const int lane = tid & 63;
  const int b = blockIdx.x;
  const int blk = b * 64;
  const int cnt = bcnt[b];

  if (tid < 65) offs[tid] = boffs[b * 65 + tid];
  for (int i = tid; i < cnt; i += 256) srcS[i] = srcsS[(size_t)b * BCAP + i];
  __syncthreads();

  // ---- gather (self from fp8 Xq)
  const int l = tid & 7, g = tid >> 3;
  const uint4* baseq = (const uint4*)Xq;
#pragma unroll
  for (int s2 = 0; s2 < 2; ++s2) {
    int nl = s2 * 32 + g;
    int node = blk + nl;
    float s[16] = {0, 0, 0, 0, 0, 0, 0, 0, 0, 0, 0, 0, 0, 0, 0, 0};
    if (node < M) {
      addf8q(s, baseq[(size_t)node * 8 + l]);
      int beg = offs[nl], c = offs[nl + 1] - beg;
      int j = 0;
      for (; j + 8 <= c; j += 8) {
        int i0 = srcS[beg + j + 0], i1 = srcS[beg + j + 1];
        int i2 = srcS[beg + j + 2], i3 = srcS[beg + j + 3];
        int i4 = srcS[beg + j + 4], i5 = srcS[beg + j + 5];
        int i6 = srcS[beg + j + 6], i7 = srcS[beg + j + 7];
        uint4 v0 = baseq[(size_t)i0 * 8 + l];
        uint4 v1 = baseq[(size_t)i1 * 8 + l];
        uint4 v2 = baseq[(size_t)i2 * 8 + l];
        uint4 v3 = baseq[(size_t)i3 * 8 + l];
        uint4 v4 = baseq[(size_t)i4 * 8 + l];
        uint4 v5 = baseq[(size_t)i5 * 8 + l];
        uint4 v6 = baseq[(size_t)i6 * 8 + l];
        uint4 v7 = baseq[(size_t)i7 * 8 + l];
        addf8q(s, v0); addf8q(s, v1); addf8q(s, v2); addf8q(s, v3);
        addf8q(s, v4); addf8q(s, v5); addf8q(s, v6); addf8q(s, v7);
      }
      if (j + 4 <= c) {
        int i0 = srcS[beg + j + 0], i1 = srcS[beg + j + 1];
        int i2 = srcS[beg + j + 2], i3 = srcS[beg + j + 3];
        uint4 v0 = baseq[(size_t)i0 * 8 + l];
        uint4 v1 = baseq[(size_t)i1 * 8 + l];
        uint4 v2 = baseq[(size_t)i2 * 8 + l];
        uint4 v3 = baseq[(size_t)i3 * 8 + l];
        addf8q(s, v0); addf8q(s, v1); addf8q(s, v2); addf8q(s, v3);
        j += 4;
      }
      if (j + 2 <= c) {
        int i0 = srcS[beg + j + 0], i1 = srcS[beg + j + 1];
        uint4 v0 = baseq[(size_t)i0 * 8 + l];
        uint4 v1 = baseq[(size_t)i1 * 8 + l];
        addf8q(s, v0); addf8q(s, v1);
        j += 2;
      }
      if (j < c) addf8q(s, baseq[(size_t)srcS[beg + j] * 8 + l]);
    }
    uint4 o0, o1;
    o0.x = pack2(s[0], s[1]);   o0.y = pack2(s[2], s[3]);
    o0.z = pack2(s[4], s[5]);   o0.w = pack2(s[6], s[7]);
    o1.x = pack2(s[8], s[9]);   o1.y = pack2(s[10], s[11]);
    o1.z = pack2(s[12], s[13]); o1.w = pack2(s[14], s[15]);
    *(uint4*)&As[nl * 136 + l * 16] = o0;
    *(uint4*)&As[nl * 136 + l * 16 + 8] = o1;
  }
  __syncthreads();

  // ---- layer-3 MFMA: 64x128, K=128
  const int w = tid >> 6;
  const int wm = w & 1, wn = w >> 1;
  const int l15 = lane & 15, quad = lane >> 4;
  const int mb = wm * 32, nb2 = wn * 64;

  v4f acc[2][4];
#pragma unroll
  for (int mf = 0; mf < 2; ++mf)
#pragma unroll
    for (int nf = 0; nf < 4; ++nf) acc[mf][nf] = (v4f)0.f;

#pragma unroll
  for (int k0 = 0; k0 < 128; k0 += 32) {
    short8 a[2], bv[4];
#pragma unroll
    for (int mf = 0; mf < 2; ++mf)
      a[mf] = *(const short8*)&As[(mb + mf * 16 + l15) * 136 + k0 + quad * 8];
#pragma unroll
    for (int nf = 0; nf < 4; ++nf)
      bv[nf] = *(const short8*)(W2T + (size_t)(nb2 + nf * 16 + l15) * 128 + quad * 8 + k0);
#pragma unroll
    for (int mf = 0; mf < 2; ++mf)
#pragma unroll
      for (int nf = 0; nf < 4; ++nf)
        acc[mf][nf] = __builtin_amdgcn_mfma_f32_16x16x32_bf16(a[mf], bv[nf], acc[mf][nf], 0, 0, 0);
  }
  __syncthreads();  // all As reads done before rewrite

  // t = relu(acc + b2) -> back into As (local rows 0..63, cols 0..127)
#pragma unroll
  for (int mf = 0; mf < 2; ++mf)
#pragma unroll
    for (int r = 0; r < 4; ++r) {
      int row = mb + mf * 16 + quad * 4 + r;
#pragma unroll
      for (int nf = 0; nf < 4; ++nf) {
        int col = nb2 + nf * 16 + l15;
        As[row * 136 + col] = f2bf(fmaxf(acc[mf][nf][r] + b2[col], 0.f));
      }
    }
  __syncthreads();

  // ---- head phase A: Hm = relu(t @ Wm1 + bm1), 64x256, K=128
  const int nbH = wn * 128;
  v4f acc2[2][8];
#pragma unroll
  for (int mf = 0; mf < 2; ++mf)
#pragma unroll
    for (int nf = 0; nf < 8; ++nf) acc2[mf][nf] = (v4f)0.f;

#pragma unroll
  for (int k0 = 0; k0 < 128; k0 += 32) {
    short8 a[2];
#pragma unroll
    for (int mf = 0; mf < 2; ++mf)
      a[mf] = *(const short8*)&As[(mb + mf * 16 + l15) * 136 + k0 + quad * 8];
#pragma unroll
    for (int nf = 0; nf < 8; ++nf) {
      short8 bb = *(const short8*)(Wm1T + (size_t)(nbH + nf * 16 + l15) * 128 + quad * 8 + k0);
#pragma unroll
      for (int mf = 0; mf < 2; ++mf)
        acc2[mf][nf] = __builtin_amdgcn_mfma_f32_16x16x32_bf16(a[mf], bb, acc2[mf][nf], 0, 0, 0);
    }
  }
  __syncthreads();  // As reads done; Hs may overwrite

#pragma unroll
  for (int mf = 0; mf < 2; ++mf)
#pragma unroll
    for (int r = 0; r < 4; ++r) {
      int row = mb + mf * 16 + quad * 4 + r;
#pragma unroll
      for (int nf = 0; nf < 8; ++nf) {
        int col = nbH + nf * 16 + l15;
        Hs[row * 264 + col] = f2bf(fmaxf(acc2[mf][nf][r] + bm1[col], 0.f));
      }
    }
  __syncthreads();

  // ---- head phase B: out = Hs @ Wm2 + bm2; 64x16, K=256; wave = 16 rows
  const int rowl = w * 16 + l15;
  const unsigned short* bp2 = Wm2T + (size_t)l15 * 256 + quad * 8;
  v4f acc3 = (v4f)0.f;
#pragma unroll
  for (int k0 = 0; k0 < 256; k0 += 32)
    acc3 = __builtin_amdgcn_mfma_f32_16x16x32_bf16(
        *(const short8*)&Hs[rowl * 264 + k0 + quad * 8],
        *(const short8*)(bp2 + k0), acc3, 0, 0, 0);
  float bb = (l15 < NOUT) ? bm2[l15] : 0.f;
#pragma unroll
  for (int r = 0; r < 4; ++r) {
    int grow = blk + w * 16 + quad * 4 + r;
    if (grow < M && l15 < NOUT) out[(size_t)grow * NOUT + l15] = acc3[r] + bb;
  }
}

// ---------------------------------------------------------------------------

extern "C" void kernel_launch(void* const* d_in, const int* in_sizes, int n_in,
                              void* d_out, int out_size, void* d_ws, size_t ws_size,
                              hipStream_t stream) {
  const float* x   = (const float*)d_in[0];
  const int*   ei  = (const int*)d_in[1];
  const float* W0  = (const float*)d_in[2];
  const float* b0  = (const float*)d_in[3];
  const float* W1  = (const float*)d_in[4];
  const float* b1  = (const float*)d_in[5];
  const float* W2  = (const float*)d_in[6];
  const float* b2  = (const float*)d_in[7];
  const float* Wm1 = (const float*)d_in[8];
  const float* bm1 = (const float*)d_in[9];
  const float* Wm2 = (const float*)d_in[10];
  const float* bm2 = (const float*)d_in[11];
  float* out = (float*)d_out;

  const int D = 128;
  const int N = in_sizes[0] / D;   // 50000
  const int E = in_sizes[1] / 2;   // 600000
  const int L = in_sizes[11];      // 10
  const int nb = (N + 63) / 64;    // 782 buckets == layer tiles

  const int* srcv = ei;
  const int* dstv = ei + E;

  char* ws = (char*)d_ws;
  size_t off = 0;
  auto alloc = [&](size_t bytes) -> void* {
    void* p = ws + off;
    off = (off + bytes + 255) & ~(size_t)255;
    return p;
  };
  int* bcnt    = (int*)alloc((size_t)MAXB * 4);
  int* bucketA = (int*)alloc((size_t)nb * BCAP * 4);
  int* srcsS   = (int*)alloc((size_t)nb * BCAP * 4);
  int* boffs   = (int*)alloc((size_t)nb * 65 * 4);
  unsigned short* xb   = (unsigned short*)alloc((size_t)N * 128 * 2);
  unsigned char*  xq   = (unsigned char*)alloc((size_t)N * 128);
  unsigned char*  h1q  = (unsigned char*)alloc((size_t)N * 128);
  unsigned char*  h2q  = (unsigned char*)alloc((size_t)N * 128);
  unsigned short* W0T  = (unsigned short*)alloc(128 * 128 * 2);
  unsigned short* W1T  = (unsigned short*)alloc(128 * 128 * 2);
  unsigned short* W2T  = (unsigned short*)alloc(128 * 128 * 2);
  unsigned short* Wm1T = (unsigned short*)alloc(256 * 128 * 2);
  unsigned short* Wm2T = (unsigned short*)alloc(16 * 256 * 2);
  (void)ws_size; (void)n_in; (void)out_size;

  const int tpb = 256;
  int n8 = N * 16;
  prep_all<<<dim3((n8 + tpb - 1) / tpb), dim3(tpb), 0, stream>>>(
      W0, W1, W2, Wm1, Wm2, W0T, W1T, W2T, Wm1T, Wm2T, x, xb, xq, n8, bcnt);

  const int nbin = 256;
  int per = (E + nbin - 1) / nbin;
  bin_edges<<<dim3(nbin), dim3(tpb), 0, stream>>>(srcv, dstv, E, per, bcnt, bucketA, nb);
  sort_buckets<<<dim3(nb), dim3(tpb), 0, stream>>>(bcnt, bucketA, srcsS, boffs);

  dim3 lgrid(nb);
  fused_layer<<<lgrid, dim3(tpb), 0, stream>>>(
      xb, xq, bcnt, srcsS, boffs, W0T, b0, h1q, N);          // L1: self bf16
  fused_layer<<<lgrid, dim3(tpb), 0, stream>>>(
      nullptr, h1q, bcnt, srcsS, boffs, W1T, b1, h2q, N);    // L2: self fp8
  fused_l3_head<<<lgrid, dim3(tpb), 0, stream>>>(
      h2q, bcnt, srcsS, boffs, W2T, b2, Wm1T, bm1, Wm2T, bm2, out, N, L);
}

// Round 7
// 202.636 us; speedup vs baseline: 1.2449x; 1.0864x over previous
//
#include <hip/hip_runtime.h>

// ---------------------------------------------------------------------------
// GIN: 3 x (bucket gather-sum + (x+agg)@W + b, relu) + MLP head, bf16 MFMA.
// r13: fragment-major weight layout. Evidence: l3_head 49.6us = 23us gather
//     wall + ~25us unexplained; the weight MFMA B-loads (rows 256B apart,
//     16 segments/instr) pay the same divergent-TA serialization as the
//     gather (r6-r10 law). Fix: prep_all stores each 16colx32k B-fragment
//     as 64 lanes x 16B CONTIGUOUS (frag*512 + lane*8) -> every weight load
//     is one coalesced 1KB instr. No LDS/occupancy change (r11's lesson).
//     Keeps r12: fp8-only hidden state, fp8 self L2/L3, bf16 self L1,
//     dwordx4 fp8 gather (8 edges/instr = fp8 floor of the gather wall).
//     6 dispatches: prep_all, bin_edges, sort_buckets, 2x fused_layer,
//     fused_l3_head.
// ---------------------------------------------------------------------------

typedef short short8 __attribute__((ext_vector_type(8)));
typedef float v4f __attribute__((ext_vector_type(4)));
typedef float v2f __attribute__((ext_vector_type(2)));

#define BCAP 1024   // bucket capacity: avg 768 edges, +9 sigma head-room
#define MAXB 1024   // >= nbuckets (782)

__device__ inline unsigned short f2bf(float f) {
  union { float f; unsigned int u; } c; c.f = f;
  unsigned int u = c.u;
  return (unsigned short)((u + 0x7fffu + ((u >> 16) & 1u)) >> 16);  // RNE
}
__device__ inline float bfbits2f(unsigned int hi) {
  union { unsigned int u; float f; } c; c.u = hi; return c.f;
}
__device__ inline unsigned int pack2(float a, float b) {
  return (unsigned int)f2bf(a) | ((unsigned int)f2bf(b) << 16);
}
__device__ inline void add8(float* s, uint4 v) {
  s[0] += bfbits2f(v.x << 16); s[1] += bfbits2f(v.x & 0xffff0000u);
  s[2] += bfbits2f(v.y << 16); s[3] += bfbits2f(v.y & 0xffff0000u);
  s[4] += bfbits2f(v.z << 16); s[5] += bfbits2f(v.z & 0xffff0000u);
  s[6] += bfbits2f(v.w << 16); s[7] += bfbits2f(v.w & 0xffff0000u);
}
// decode 16 fp8 (e4m3, HW format) and accumulate into s[0..15]
__device__ inline void addf8q(float* s, uint4 v) {
  v2f p;
  p = __builtin_amdgcn_cvt_pk_f32_fp8(v.x, false); s[0]  += p.x; s[1]  += p.y;
  p = __builtin_amdgcn_cvt_pk_f32_fp8(v.x, true);  s[2]  += p.x; s[3]  += p.y;
  p = __builtin_amdgcn_cvt_pk_f32_fp8(v.y, false); s[4]  += p.x; s[5]  += p.y;
  p = __builtin_amdgcn_cvt_pk_f32_fp8(v.y, true);  s[6]  += p.x; s[7]  += p.y;
  p = __builtin_amdgcn_cvt_pk_f32_fp8(v.z, false); s[8]  += p.x; s[9]  += p.y;
  p = __builtin_amdgcn_cvt_pk_f32_fp8(v.z, true);  s[10] += p.x; s[11] += p.y;
  p = __builtin_amdgcn_cvt_pk_f32_fp8(v.w, false); s[12] += p.x; s[13] += p.y;
  p = __builtin_amdgcn_cvt_pk_f32_fp8(v.w, true);  s[14] += p.x; s[15] += p.y;
}
__device__ inline unsigned char f2fp8(float v) {
  return (unsigned char)(__builtin_amdgcn_cvt_pk_fp8_f32(v, v, 0, false) & 0xff);
}
__device__ inline int wave_incl_scan_int(int v, int lane) {
#pragma unroll
  for (int off = 1; off < 64; off <<= 1) {
    int t = __shfl_up(v, off, 64);
    if (lane >= off) v += t;
  }
  return v;
}

// ------------------------- prep: weights + x->bf16/fp8 + zero bcnt ----------
// Weight layouts are FRAGMENT-MAJOR: for each (16-col x 32-k) MFMA B-frag,
// lane l (l15=l&15, quad=l>>4) holds cols nfr*16+l15, k = kq*32+quad*8+j.
// Stored at frag*512 + l*8 + j -> kernel loads are coalesced 1KB.
__global__ __launch_bounds__(256) void prep_all(
    const float* __restrict__ W0, const float* __restrict__ W1, const float* __restrict__ W2,
    const float* __restrict__ Wm1, const float* __restrict__ Wm2,
    unsigned short* __restrict__ W0T, unsigned short* __restrict__ W1T,
    unsigned short* __restrict__ W2T, unsigned short* __restrict__ Wm1T,
    unsigned short* __restrict__ Wm2T,
    const float* __restrict__ x, unsigned short* __restrict__ xb,
    unsigned char* __restrict__ xq, int n8,
    int* __restrict__ bcnt) {
  int i = blockIdx.x * 256 + threadIdx.x;
  if (i < MAXB) bcnt[i] = 0;
  if (i < n8) {
    const float4* p = (const float4*)x;
    float4 a = p[2 * (size_t)i], b = p[2 * (size_t)i + 1];
    uint4 o;
    o.x = pack2(a.x, a.y); o.y = pack2(a.z, a.w);
    o.z = pack2(b.x, b.y); o.w = pack2(b.z, b.w);
    ((uint4*)xb)[i] = o;
    unsigned int lo = 0, hi = 0;
    lo = __builtin_amdgcn_cvt_pk_fp8_f32(a.x, a.y, lo, false);
    lo = __builtin_amdgcn_cvt_pk_fp8_f32(a.z, a.w, lo, true);
    hi = __builtin_amdgcn_cvt_pk_fp8_f32(b.x, b.y, hi, false);
    hi = __builtin_amdgcn_cvt_pk_fp8_f32(b.z, b.w, hi, true);
    uint2 q; q.x = lo; q.y = hi;
    ((uint2*)xq)[i] = q;
  }
  if (i < 49152) {                       // 3 x [128,128]: frag = kq*8 + nfr
    int w = i / 16384, r = i % 16384;
    int frag = r >> 9, l = (r >> 3) & 63, j = r & 7;
    int kq = frag >> 3, nfr = frag & 7;
    int nn = nfr * 16 + (l & 15);
    int k  = kq * 32 + (l >> 4) * 8 + j;
    const float* W = (w == 0) ? W0 : (w == 1) ? W1 : W2;
    unsigned short* O = (w == 0) ? W0T : (w == 1) ? W1T : W2T;
    O[r] = f2bf(W[k * 128 + nn]);
  } else if (i < 49152 + 32768) {        // Wm1 [128,256]: frag = kq*16 + nfr
    int r = i - 49152;
    int frag = r >> 9, l = (r >> 3) & 63, j = r & 7;
    int kq = frag >> 4, nfr = frag & 15;
    int nn = nfr * 16 + (l & 15);
    int k  = kq * 32 + (l >> 4) * 8 + j;
    Wm1T[r] = f2bf(Wm1[k * 256 + nn]);
  } else if (i < 49152 + 32768 + 4096) { // Wm2 [256,10]: frag = kq (16 cols pad)
    int r = i - 49152 - 32768;
    int kq = r >> 9, l = (r >> 3) & 63, j = r & 7;
    int nn = l & 15;
    int k  = kq * 32 + (l >> 4) * 8 + j;
    Wm2T[r] = (nn < 10) ? f2bf(Wm2[k * 10 + nn]) : (unsigned short)0;
  }
}

// ------------------------- bin edges into 64-node buckets -------------------
// entry = (src << 6) | (dst & 63); bucket = dst >> 6.
__global__ __launch_bounds__(256) void bin_edges(
    const int* __restrict__ src, const int* __restrict__ dst, int E, int per,
    int* __restrict__ bcnt, int* __restrict__ bucketA, int nbuckets) {
  __shared__ int hist[MAXB];
  __shared__ int base[MAXB];
  const int tid = threadIdx.x;
  const int e0 = blockIdx.x * per;
  const int e1 = (e0 + per < E) ? e0 + per : E;
  for (int j = tid; j < nbuckets; j += 256) hist[j] = 0;
  __syncthreads();
  for (int i = e0 + tid; i < e1; i += 256) atomicAdd(&hist[dst[i] >> 6], 1);
  __syncthreads();
  for (int j = tid; j < nbuckets; j += 256) {
    int h = hist[j];
    base[j] = h ? atomicAdd(&bcnt[j], h) : 0;
  }
  __syncthreads();
  for (int i = e0 + tid; i < e1; i += 256) {
    int d = dst[i], s = src[i];
    int b = d >> 6;
    int r = atomicAdd(&base[b], 1);
    bucketA[(size_t)b * BCAP + r] = (s << 6) | (d & 63);
  }
}

// ------------------------- per-bucket counting sort (once) ------------------
// Produces srcsS[b*BCAP + p] sorted by local node, boffs[b*65 + 0..64].
__global__ __launch_bounds__(256) void sort_buckets(
    const int* __restrict__ bcnt, const int* __restrict__ bucketA,
    int* __restrict__ srcsS, int* __restrict__ boffs) {
  __shared__ int rawE[BCAP];
  __shared__ int hist[64], cur[64], offs[65];
  const int tid = threadIdx.x;
  const int b = blockIdx.x;
  const int cnt = bcnt[b];
  for (int i = tid; i < cnt; i += 256) rawE[i] = bucketA[(size_t)b * BCAP + i];
  if (tid < 64) hist[tid] = 0;
  __syncthreads();
  for (int i = tid; i < cnt; i += 256) atomicAdd(&hist[rawE[i] & 63], 1);
  __syncthreads();
  if (tid < 64) {
    int v = hist[tid];
    int incl = wave_incl_scan_int(v, tid);
    offs[tid] = incl - v;
    cur[tid] = incl - v;
    if (tid == 63) offs[64] = incl;
  }
  __syncthreads();
  for (int i = tid; i < cnt; i += 256) {
    int e = rawE[i];
    int p = atomicAdd(&cur[e & 63], 1);
    srcsS[(size_t)b * BCAP + p] = e >> 6;
  }
  if (tid < 65) boffs[b * 65 + tid] = offs[tid];
}

// ------------------------- fused layer (layers 1,2) -------------------------
// Block = bucket = 64 nodes. Neighbor gather from fp8 Xq via dwordx4: 8
// lanes x 16B per 128B row -> 8 edges per wave instr. Self term: bf16 Xb
// if non-null (layer 1, exact), else fp8 Xq. 2 sweeps x 32 nodes; NO
// barriers in gather. MFMA 64x128 (2x2 waves, 32m x 64n, K=128); weight
// B-fragments coalesced (frag*512 + lane*8). fp8 out.
__global__ __launch_bounds__(256) void fused_layer(
    const unsigned short* __restrict__ Xb, const unsigned char* __restrict__ Xq,
    const int* __restrict__ bcnt,
    const int* __restrict__ srcsS, const int* __restrict__ boffs,
    const unsigned short* __restrict__ BT, const float* __restrict__ bias,
    unsigned char* __restrict__ Cq, int M) {
  __shared__ __align__(16) unsigned short As[64 * 136];
  __shared__ int srcS[BCAP];
  __shared__ int offs[65];
  const int tid = threadIdx.x;
  const int lane = tid & 63;
  const int b = blockIdx.x;
  const int blk = b * 64;
  const int cnt = bcnt[b];

  if (tid < 65) offs[tid] = boffs[b * 65 + tid];
  for (int i = tid; i < cnt; i += 256) srcS[i] = srcsS[(size_t)b * BCAP + i];
  __syncthreads();

  // ---- gather: 2 sweeps x 32 nodes; 8 lanes x 16B fp8 per row
  const int l = tid & 7, g = tid >> 3;
  const uint4* baseb = (const uint4*)Xb;  // bf16 rows: 16 x uint4 (may be null)
  const uint4* baseq = (const uint4*)Xq;  // fp8 rows:   8 x uint4
#pragma unroll
  for (int s2 = 0; s2 < 2; ++s2) {
    int nl = s2 * 32 + g;
    int node = blk + nl;
    float s[16] = {0, 0, 0, 0, 0, 0, 0, 0, 0, 0, 0, 0, 0, 0, 0, 0};
    if (node < M) {
      if (Xb) {
        add8(s, baseb[(size_t)node * 16 + l * 2]);
        add8(s + 8, baseb[(size_t)node * 16 + l * 2 + 1]);
      } else {
        addf8q(s, baseq[(size_t)node * 8 + l]);
      }
      int beg = offs[nl], c = offs[nl + 1] - beg;
      int j = 0;
      for (; j + 8 <= c; j += 8) {
        int i0 = srcS[beg + j + 0], i1 = srcS[beg + j + 1];
        int i2 = srcS[beg + j + 2], i3 = srcS[beg + j + 3];
        int i4 = srcS[beg + j + 4], i5 = srcS[beg + j + 5];
        int i6 = srcS[beg + j + 6], i7 = srcS[beg + j + 7];
        uint4 v0 = baseq[(size_t)i0 * 8 + l];
        uint4 v1 = baseq[(size_t)i1 * 8 + l];
        uint4 v2 = baseq[(size_t)i2 * 8 + l];
        uint4 v3 = baseq[(size_t)i3 * 8 + l];
        uint4 v4 = baseq[(size_t)i4 * 8 + l];
        uint4 v5 = baseq[(size_t)i5 * 8 + l];
        uint4 v6 = baseq[(size_t)i6 * 8 + l];
        uint4 v7 = baseq[(size_t)i7 * 8 + l];
        addf8q(s, v0); addf8q(s, v1); addf8q(s, v2); addf8q(s, v3);
        addf8q(s, v4); addf8q(s, v5); addf8q(s, v6); addf8q(s, v7);
      }
      if (j + 4 <= c) {
        int i0 = srcS[beg + j + 0], i1 = srcS[beg + j + 1];
        int i2 = srcS[beg + j + 2], i3 = srcS[beg + j + 3];
        uint4 v0 = baseq[(size_t)i0 * 8 + l];
        uint4 v1 = baseq[(size_t)i1 * 8 + l];
        uint4 v2 = baseq[(size_t)i2 * 8 + l];
        uint4 v3 = baseq[(size_t)i3 * 8 + l];
        addf8q(s, v0); addf8q(s, v1); addf8q(s, v2); addf8q(s, v3);
        j += 4;
      }
      if (j + 2 <= c) {
        int i0 = srcS[beg + j + 0], i1 = srcS[beg + j + 1];
        uint4 v0 = baseq[(size_t)i0 * 8 + l];
        uint4 v1 = baseq[(size_t)i1 * 8 + l];
        addf8q(s, v0); addf8q(s, v1);
        j += 2;
      }
      if (j < c) addf8q(s, baseq[(size_t)srcS[beg + j] * 8 + l]);
    }
    uint4 o0, o1;
    o0.x = pack2(s[0], s[1]);   o0.y = pack2(s[2], s[3]);
    o0.z = pack2(s[4], s[5]);   o0.w = pack2(s[6], s[7]);
    o1.x = pack2(s[8], s[9]);   o1.y = pack2(s[10], s[11]);
    o1.z = pack2(s[12], s[13]); o1.w = pack2(s[14], s[15]);
    *(uint4*)&As[nl * 136 + l * 16] = o0;
    *(uint4*)&As[nl * 136 + l * 16 + 8] = o1;
  }
  __syncthreads();

  // ---- MFMA: 4 waves 2x2; wave tile 32m x 64n; K=128; coalesced B-frags
  const int w = tid >> 6;
  const int wm = w & 1, wn = w >> 1;
  const int l15 = lane & 15, quad = lane >> 4;
  const int mb = wm * 32, nb2 = wn * 64;

  v4f acc[2][4];
#pragma unroll
  for (int mf = 0; mf < 2; ++mf)
#pragma unroll
    for (int nf = 0; nf < 4; ++nf) acc[mf][nf] = (v4f)0.f;

#pragma unroll
  for (int k0 = 0; k0 < 128; k0 += 32) {
    const int kq = k0 >> 5;
    short8 a[2], bv[4];
#pragma unroll
    for (int mf = 0; mf < 2; ++mf)
      a[mf] = *(const short8*)&As[(mb + mf * 16 + l15) * 136 + k0 + quad * 8];
#pragma unroll
    for (int nf = 0; nf < 4; ++nf)
      bv[nf] = *(const short8*)(BT + (size_t)(kq * 8 + wn * 4 + nf) * 512 + lane * 8);
#pragma unroll
    for (int mf = 0; mf < 2; ++mf)
#pragma unroll
      for (int nf = 0; nf < 4; ++nf)
        acc[mf][nf] = __builtin_amdgcn_mfma_f32_16x16x32_bf16(a[mf], bv[nf], acc[mf][nf], 0, 0, 0);
  }

#pragma unroll
  for (int mf = 0; mf < 2; ++mf) {
#pragma unroll
    for (int r = 0; r < 4; ++r) {
      int grow = blk + mb + mf * 16 + quad * 4 + r;
      if (grow >= M) continue;
#pragma unroll
      for (int nf = 0; nf < 4; ++nf) {
        int gcol = nb2 + nf * 16 + l15;
        float v = fmaxf(acc[mf][nf][r] + bias[gcol], 0.f);
        Cq[(size_t)grow * 128 + gcol] = f2fp8(v);
      }
    }
  }
}

// ------------------------- fused layer 3 + MLP head -------------------------
// fp8-self gather + layer-3 MFMA, then head in LDS (34KB union). All weight
// B-fragments coalesced.
__global__ __launch_bounds__(256) void fused_l3_head(
    const unsigned char* __restrict__ Xq,
    const int* __restrict__ bcnt,
    const int* __restrict__ srcsS, const int* __restrict__ boffs,
    const unsigned short* __restrict__ W2T, const float* __restrict__ b2,
    const unsigned short* __restrict__ Wm1T, const float* __restrict__ bm1,
    const unsigned short* __restrict__ Wm2T, const float* __restrict__ bm2,
    float* __restrict__ out, int M, int NOUT) {
  __shared__ __align__(16) unsigned char lds[64 * 264 * 2];  // Hs 33.8KB
  unsigned short* As = (unsigned short*)lds;                 // 17.4KB
  int* srcS = (int*)(lds + 64 * 136 * 2);                    // 4KB after As
  unsigned short* Hs = (unsigned short*)lds;                 // aliases both
  __shared__ int offs[65];
  const int tid = threadIdx.x;
  const int lane = tid & 63;
  const int b = blockIdx.x;
  const int blk = b * 64;
  const int cnt = bcnt[b];

  if (tid < 65) offs[tid] = boffs[b * 65 + tid];
  for (int i = tid; i < cnt; i += 256) srcS[i] = srcsS[(size_t)b * BCAP + i];
  __syncthreads();

  // ---- gather (self from fp8 Xq)
  const int l = tid & 7, g = tid >> 3;
  const uint4* baseq = (const uint4*)Xq;
#pragma unroll
  for (int s2 = 0; s2 < 2; ++s2) {
    int nl = s2 * 32 + g;
    int node = blk + nl;
    float s[16] = {0, 0, 0, 0, 0, 0, 0, 0, 0, 0, 0, 0, 0, 0, 0, 0};
    if (node < M) {
      addf8q(s, baseq[(size_t)node * 8 + l]);
      int beg = offs[nl], c = offs[nl + 1] - beg;
      int j = 0;
      for (; j + 8 <= c; j += 8) {
        int i0 = srcS[beg + j + 0], i1 = srcS[beg + j + 1];
        int i2 = srcS[beg + j + 2], i3 = srcS[beg + j + 3];
        int i4 = srcS[beg + j + 4], i5 = srcS[beg + j + 5];
        int i6 = srcS[beg + j + 6], i7 = srcS[beg + j + 7];
        uint4 v0 = baseq[(size_t)i0 * 8 + l];
        uint4 v1 = baseq[(size_t)i1 * 8 + l];
        uint4 v2 = baseq[(size_t)i2 * 8 + l];
        uint4 v3 = baseq[(size_t)i3 * 8 + l];
        uint4 v4 = baseq[(size_t)i4 * 8 + l];
        uint4 v5 = baseq[(size_t)i5 * 8 + l];
        uint4 v6 = baseq[(size_t)i6 * 8 + l];
        uint4 v7 = baseq[(size_t)i7 * 8 + l];
        addf8q(s, v0); addf8q(s, v1); addf8q(s, v2); addf8q(s, v3);
        addf8q(s, v4); addf8q(s, v5); addf8q(s, v6); addf8q(s, v7);
      }
      if (j + 4 <= c) {
        int i0 = srcS[beg + j + 0], i1 = srcS[beg + j + 1];
        int i2 = srcS[beg + j + 2], i3 = srcS[beg + j + 3];
        uint4 v0 = baseq[(size_t)i0 * 8 + l];
        uint4 v1 = baseq[(size_t)i1 * 8 + l];
        uint4 v2 = baseq[(size_t)i2 * 8 + l];
        uint4 v3 = baseq[(size_t)i3 * 8 + l];
        addf8q(s, v0); addf8q(s, v1); addf8q(s, v2); addf8q(s, v3);
        j += 4;
      }
      if (j + 2 <= c) {
        int i0 = srcS[beg + j + 0], i1 = srcS[beg + j + 1];
        uint4 v0 = baseq[(size_t)i0 * 8 + l];
        uint4 v1 = baseq[(size_t)i1 * 8 + l];
        addf8q(s, v0); addf8q(s, v1);
        j += 2;
      }
      if (j < c) addf8q(s, baseq[(size_t)srcS[beg + j] * 8 + l]);
    }
    uint4 o0, o1;
    o0.x = pack2(s[0], s[1]);   o0.y = pack2(s[2], s[3]);
    o0.z = pack2(s[4], s[5]);   o0.w = pack2(s[6], s[7]);
    o1.x = pack2(s[8], s[9]);   o1.y = pack2(s[10], s[11]);
    o1.z = pack2(s[12], s[13]); o1.w = pack2(s[14], s[15]);
    *(uint4*)&As[nl * 136 + l * 16] = o0;
    *(uint4*)&As[nl * 136 + l * 16 + 8] = o1;
  }
  __syncthreads();

  // ---- layer-3 MFMA: 64x128, K=128; coalesced W2 frags
  const int w = tid >> 6;
  const int wm = w & 1, wn = w >> 1;
  const int l15 = lane & 15, quad = lane >> 4;
  const int mb = wm * 32, nb2 = wn * 64;

  v4f acc[2][4];
#pragma unroll
  for (int mf = 0; mf < 2; ++mf)
#pragma unroll
    for (int nf = 0; nf < 4; ++nf) acc[mf][nf] = (v4f)0.f;

#pragma unroll
  for (int k0 = 0; k0 < 128; k0 += 32) {
    const int kq = k0 >> 5;
    short8 a[2], bv[4];
#pragma unroll
    for (int mf = 0; mf < 2; ++mf)
      a[mf] = *(const short8*)&As[(mb + mf * 16 + l15) * 136 + k0 + quad * 8];
#pragma unroll
    for (int nf = 0; nf < 4; ++nf)
      bv[nf] = *(const short8*)(W2T + (size_t)(kq * 8 + wn * 4 + nf) * 512 + lane * 8);
#pragma unroll
    for (int mf = 0; mf < 2; ++mf)
#pragma unroll
      for (int nf = 0; nf < 4; ++nf)
        acc[mf][nf] = __builtin_amdgcn_mfma_f32_16x16x32_bf16(a[mf], bv[nf], acc[mf][nf], 0, 0, 0);
  }
  __syncthreads();  // all As reads done before rewrite

  // t = relu(acc + b2) -> back into As (local rows 0..63, cols 0..127)
#pragma unroll
  for (int mf = 0; mf < 2; ++mf)
#pragma unroll
    for (int r = 0; r < 4; ++r) {
      int row = mb + mf * 16 + quad * 4 + r;
#pragma unroll
      for (int nf = 0; nf < 4; ++nf) {
        int col = nb2 + nf * 16 + l15;
        As[row * 136 + col] = f2bf(fmaxf(acc[mf][nf][r] + b2[col], 0.f));
      }
    }
  __syncthreads();

  // ---- head phase A: Hm = relu(t @ Wm1 + bm1), 64x256, K=128; coalesced
  const int nbH = wn * 128;
  v4f acc2[2][8];
#pragma unroll
  for (int mf = 0; mf < 2; ++mf)
#pragma unroll
    for (int nf = 0; nf < 8; ++nf) acc2[mf][nf] = (v4f)0.f;

#pragma unroll
  for (int k0 = 0; k0 < 128; k0 += 32) {
    const int kq = k0 >> 5;
    short8 a[2];
#pragma unroll
    for (int mf = 0; mf < 2; ++mf)
      a[mf] = *(const short8*)&As[(mb + mf * 16 + l15) * 136 + k0 + quad * 8];
#pragma unroll
    for (int nf = 0; nf < 8; ++nf) {
      short8 bb = *(const short8*)(Wm1T + (size_t)(kq * 16 + wn * 8 + nf) * 512 + lane * 8);
#pragma unroll
      for (int mf = 0; mf < 2; ++mf)
        acc2[mf][nf] = __builtin_amdgcn_mfma_f32_16x16x32_bf16(a[mf], bb, acc2[mf][nf], 0, 0, 0);
    }
  }
  __syncthreads();  // As reads done; Hs may overwrite

#pragma unroll
  for (int mf = 0; mf < 2; ++mf)
#pragma unroll
    for (int r = 0; r < 4; ++r) {
      int row = mb + mf * 16 + quad * 4 + r;
#pragma unroll
      for (int nf = 0; nf < 8; ++nf) {
        int col = nbH + nf * 16 + l15;
        Hs[row * 264 + col] = f2bf(fmaxf(acc2[mf][nf][r] + bm1[col], 0.f));
      }
    }
  __syncthreads();

  // ---- head phase B: out = Hs @ Wm2 + bm2; 64x16, K=256; coalesced frags
  const int rowl = w * 16 + l15;
  v4f acc3 = (v4f)0.f;
#pragma unroll
  for (int k0 = 0; k0 < 256; k0 += 32)
    acc3 = __builtin_amdgcn_mfma_f32_16x16x32_bf16(
        *(const short8*)&Hs[rowl * 264 + k0 + quad * 8],
        *(const short8*)(Wm2T + (size_t)(k0 >> 5) * 512 + lane * 8), acc3, 0, 0, 0);
  float bb = (l15 < NOUT) ? bm2[l15] : 0.f;
#pragma unroll
  for (int r = 0; r < 4; ++r) {
    int grow = blk + w * 16 + quad * 4 + r;
    if (grow < M && l15 < NOUT) out[(size_t)grow * NOUT + l15] = acc3[r] + bb;
  }
}

// ---------------------------------------------------------------------------

extern "C" void kernel_launch(void* const* d_in, const int* in_sizes, int n_in,
                              void* d_out, int out_size, void* d_ws, size_t ws_size,
                              hipStream_t stream) {
  const float* x   = (const float*)d_in[0];
  const int*   ei  = (const int*)d_in[1];
  const float* W0  = (const float*)d_in[2];
  const float* b0  = (const float*)d_in[3];
  const float* W1  = (const float*)d_in[4];
  const float* b1  = (const float*)d_in[5];
  const float* W2  = (const float*)d_in[6];
  const float* b2  = (const float*)d_in[7];
  const float* Wm1 = (const float*)d_in[8];
  const float* bm1 = (const float*)d_in[9];
  const float* Wm2 = (const float*)d_in[10];
  const float* bm2 = (const float*)d_in[11];
  float* out = (float*)d_out;

  const int D = 128;
  const int N = in_sizes[0] / D;   // 50000
  const int E = in_sizes[1] / 2;   // 600000
  const int L = in_sizes[11];      // 10
  const int nb = (N + 63) / 64;    // 782 buckets == layer tiles

  const int* srcv = ei;
  const int* dstv = ei + E;

  char* ws = (char*)d_ws;
  size_t off = 0;
  auto alloc = [&](size_t bytes) -> void* {
    void* p = ws + off;
    off = (off + bytes + 255) & ~(size_t)255;
    return p;
  };
  int* bcnt    = (int*)alloc((size_t)MAXB * 4);
  int* bucketA = (int*)alloc((size_t)nb * BCAP * 4);
  int* srcsS   = (int*)alloc((size_t)nb * BCAP * 4);
  int* boffs   = (int*)alloc((size_t)nb * 65 * 4);
  unsigned short* xb   = (unsigned short*)alloc((size_t)N * 128 * 2);
  unsigned char*  xq   = (unsigned char*)alloc((size_t)N * 128);
  unsigned char*  h1q  = (unsigned char*)alloc((size_t)N * 128);
  unsigned char*  h2q  = (unsigned char*)alloc((size_t)N * 128);
  unsigned short* W0T  = (unsigned short*)alloc(128 * 128 * 2);
  unsigned short* W1T  = (unsigned short*)alloc(128 * 128 * 2);
  unsigned short* W2T  = (unsigned short*)alloc(128 * 128 * 2);
  unsigned short* Wm1T = (unsigned short*)alloc(256 * 128 * 2);
  unsigned short* Wm2T = (unsigned short*)alloc(16 * 256 * 2);
  (void)ws_size; (void)n_in; (void)out_size;

  const int tpb = 256;
  int n8 = N * 16;
  prep_all<<<dim3((n8 + tpb - 1) / tpb), dim3(tpb), 0, stream>>>(
      W0, W1, W2, Wm1, Wm2, W0T, W1T, W2T, Wm1T, Wm2T, x, xb, xq, n8, bcnt);

  const int nbin = 256;
  int per = (E + nbin - 1) / nbin;
  bin_edges<<<dim3(nbin), dim3(tpb), 0, stream>>>(srcv, dstv, E, per, bcnt, bucketA, nb);
  sort_buckets<<<dim3(nb), dim3(tpb), 0, stream>>>(bcnt, bucketA, srcsS, boffs);

  dim3 lgrid(nb);
  fused_layer<<<lgrid, dim3(tpb), 0, stream>>>(
      xb, xq, bcnt, srcsS, boffs, W0T, b0, h1q, N);          // L1: self bf16
  fused_layer<<<lgrid, dim3(tpb), 0, stream>>>(
      nullptr, h1q, bcnt, srcsS, boffs, W1T, b1, h2q, N);    // L2: self fp8
  fused_l3_head<<<lgrid, dim3(tpb), 0, stream>>>(
      h2q, bcnt, srcsS, boffs, W2T, b2, Wm1T, bm1, Wm2T, bm2, out, N, L);
}

// Round 8
// 201.083 us; speedup vs baseline: 1.2545x; 1.0077x over previous
//
#include <hip/hip_runtime.h>

// ---------------------------------------------------------------------------
// GIN: 3 x (bucket gather-sum + (x+agg)@W + b, relu) + MLP head, bf16 MFMA.
// r14: (a) FL epilogue: LDS-staged coalesced fp8 stores (was 128 byte-store
//     wave-instrs/block @ 64B each -- testing whether scattered STORES pay
//     the same ~185cyc/instr wall as scattered loads, r6-r10 law). Now
//     stage 8KB into As (dead after MFMA) -> 2 coalesced dwordx4/thread.
//     (b) prep_all+bin_edges merged into one dispatch (independent work;
//     overlap streaming with scattered atomics); bcnt zero via memsetAsync.
//     (c) bin part 512 blocks. l3_head untouched (control, expect ~50us).
//     Keeps r13: frag-major weights, fp8-only hidden state, dwordx4 fp8
//     gather (8 edges/instr = fp8 floor).
//     5 dispatches + memset: prep_bin, sort_buckets, 2x fused_layer,
//     fused_l3_head.
// ---------------------------------------------------------------------------

typedef short short8 __attribute__((ext_vector_type(8)));
typedef float v4f __attribute__((ext_vector_type(4)));
typedef float v2f __attribute__((ext_vector_type(2)));

#define BCAP 1024   // bucket capacity: avg 768 edges, +9 sigma head-room
#define MAXB 1024   // >= nbuckets (782)
#define NBIN 512    // edge-binning blocks

__device__ inline unsigned short f2bf(float f) {
  union { float f; unsigned int u; } c; c.f = f;
  unsigned int u = c.u;
  return (unsigned short)((u + 0x7fffu + ((u >> 16) & 1u)) >> 16);  // RNE
}
__device__ inline float bfbits2f(unsigned int hi) {
  union { unsigned int u; float f; } c; c.u = hi; return c.f;
}
__device__ inline unsigned int pack2(float a, float b) {
  return (unsigned int)f2bf(a) | ((unsigned int)f2bf(b) << 16);
}
__device__ inline void add8(float* s, uint4 v) {
  s[0] += bfbits2f(v.x << 16); s[1] += bfbits2f(v.x & 0xffff0000u);
  s[2] += bfbits2f(v.y << 16); s[3] += bfbits2f(v.y & 0xffff0000u);
  s[4] += bfbits2f(v.z << 16); s[5] += bfbits2f(v.z & 0xffff0000u);
  s[6] += bfbits2f(v.w << 16); s[7] += bfbits2f(v.w & 0xffff0000u);
}
// decode 16 fp8 (e4m3, HW format) and accumulate into s[0..15]
__device__ inline void addf8q(float* s, uint4 v) {
  v2f p;
  p = __builtin_amdgcn_cvt_pk_f32_fp8(v.x, false); s[0]  += p.x; s[1]  += p.y;
  p = __builtin_amdgcn_cvt_pk_f32_fp8(v.x, true);  s[2]  += p.x; s[3]  += p.y;
  p = __builtin_amdgcn_cvt_pk_f32_fp8(v.y, false); s[4]  += p.x; s[5]  += p.y;
  p = __builtin_amdgcn_cvt_pk_f32_fp8(v.y, true);  s[6]  += p.x; s[7]  += p.y;
  p = __builtin_amdgcn_cvt_pk_f32_fp8(v.z, false); s[8]  += p.x; s[9]  += p.y;
  p = __builtin_amdgcn_cvt_pk_f32_fp8(v.z, true);  s[10] += p.x; s[11] += p.y;
  p = __builtin_amdgcn_cvt_pk_f32_fp8(v.w, false); s[12] += p.x; s[13] += p.y;
  p = __builtin_amdgcn_cvt_pk_f32_fp8(v.w, true);  s[14] += p.x; s[15] += p.y;
}
__device__ inline unsigned char f2fp8(float v) {
  return (unsigned char)(__builtin_amdgcn_cvt_pk_fp8_f32(v, v, 0, false) & 0xff);
}
__device__ inline int wave_incl_scan_int(int v, int lane) {
#pragma unroll
  for (int off = 1; off < 64; off <<= 1) {
    int t = __shfl_up(v, off, 64);
    if (lane >= off) v += t;
  }
  return v;
}

// ------------- merged prep (weights + x->bf16/fp8) & edge binning -----------
// Blocks [0,PB): prep.  Blocks [PB,PB+NBIN): bin edges into 64-node buckets.
// entry = (src << 6) | (dst & 63); bucket = dst >> 6.  bcnt pre-zeroed.
__global__ __launch_bounds__(256) void prep_bin(
    const float* __restrict__ W0, const float* __restrict__ W1, const float* __restrict__ W2,
    const float* __restrict__ Wm1, const float* __restrict__ Wm2,
    unsigned short* __restrict__ W0T, unsigned short* __restrict__ W1T,
    unsigned short* __restrict__ W2T, unsigned short* __restrict__ Wm1T,
    unsigned short* __restrict__ Wm2T,
    const float* __restrict__ x, unsigned short* __restrict__ xb,
    unsigned char* __restrict__ xq, int n8, int PB,
    const int* __restrict__ src, const int* __restrict__ dst, int E, int per,
    int* __restrict__ bcnt, int* __restrict__ bucketA, int nbuckets) {
  __shared__ int hist[MAXB];
  __shared__ int base[MAXB];
  const int tid = threadIdx.x;
  if (blockIdx.x < PB) {
    // ---- prep branch
    int i = blockIdx.x * 256 + tid;
    if (i < n8) {
      const float4* p = (const float4*)x;
      float4 a = p[2 * (size_t)i], b = p[2 * (size_t)i + 1];
      uint4 o;
      o.x = pack2(a.x, a.y); o.y = pack2(a.z, a.w);
      o.z = pack2(b.x, b.y); o.w = pack2(b.z, b.w);
      ((uint4*)xb)[i] = o;
      unsigned int lo = 0, hi = 0;
      lo = __builtin_amdgcn_cvt_pk_fp8_f32(a.x, a.y, lo, false);
      lo = __builtin_amdgcn_cvt_pk_fp8_f32(a.z, a.w, lo, true);
      hi = __builtin_amdgcn_cvt_pk_fp8_f32(b.x, b.y, hi, false);
      hi = __builtin_amdgcn_cvt_pk_fp8_f32(b.z, b.w, hi, true);
      uint2 q; q.x = lo; q.y = hi;
      ((uint2*)xq)[i] = q;
    }
    if (i < 49152) {                       // 3 x [128,128]: frag = kq*8 + nfr
      int w = i / 16384, r = i % 16384;
      int frag = r >> 9, l = (r >> 3) & 63, j = r & 7;
      int kq = frag >> 3, nfr = frag & 7;
      int nn = nfr * 16 + (l & 15);
      int k  = kq * 32 + (l >> 4) * 8 + j;
      const float* W = (w == 0) ? W0 : (w == 1) ? W1 : W2;
      unsigned short* O = (w == 0) ? W0T : (w == 1) ? W1T : W2T;
      O[r] = f2bf(W[k * 128 + nn]);
    } else if (i < 49152 + 32768) {        // Wm1 [128,256]: frag = kq*16 + nfr
      int r = i - 49152;
      int frag = r >> 9, l = (r >> 3) & 63, j = r & 7;
      int kq = frag >> 4, nfr = frag & 15;
      int nn = nfr * 16 + (l & 15);
      int k  = kq * 32 + (l >> 4) * 8 + j;
      Wm1T[r] = f2bf(Wm1[k * 256 + nn]);
    } else if (i < 49152 + 32768 + 4096) { // Wm2 [256,10]: frag = kq, pad 16
      int r = i - 49152 - 32768;
      int kq = r >> 9, l = (r >> 3) & 63, j = r & 7;
      int nn = l & 15;
      int k  = kq * 32 + (l >> 4) * 8 + j;
      Wm2T[r] = (nn < 10) ? f2bf(Wm2[k * 10 + nn]) : (unsigned short)0;
    }
  } else {
    // ---- bin branch
    const int bb = blockIdx.x - PB;
    const int e0 = bb * per;
    const int e1 = (e0 + per < E) ? e0 + per : E;
    for (int j = tid; j < nbuckets; j += 256) hist[j] = 0;
    __syncthreads();
    for (int i = e0 + tid; i < e1; i += 256) atomicAdd(&hist[dst[i] >> 6], 1);
    __syncthreads();
    for (int j = tid; j < nbuckets; j += 256) {
      int h = hist[j];
      base[j] = h ? atomicAdd(&bcnt[j], h) : 0;
    }
    __syncthreads();
    for (int i = e0 + tid; i < e1; i += 256) {
      int d = dst[i], s = src[i];
      int b = d >> 6;
      int r = atomicAdd(&base[b], 1);
      bucketA[(size_t)b * BCAP + r] = (s << 6) | (d & 63);
    }
  }
}

// ------------------------- per-bucket counting sort (once) ------------------
// Produces srcsS[b*BCAP + p] sorted by local node, boffs[b*65 + 0..64].
__global__ __launch_bounds__(256) void sort_buckets(
    const int* __restrict__ bcnt, const int* __restrict__ bucketA,
    int* __restrict__ srcsS, int* __restrict__ boffs) {
  __shared__ int rawE[BCAP];
  __shared__ int hist[64], cur[64], offs[65];
  const int tid = threadIdx.x;
  const int b = blockIdx.x;
  const int cnt = bcnt[b];
  for (int i = tid; i < cnt; i += 256) rawE[i] = bucketA[(size_t)b * BCAP + i];
  if (tid < 64) hist[tid] = 0;
  __syncthreads();
  for (int i = tid; i < cnt; i += 256) atomicAdd(&hist[rawE[i] & 63], 1);
  __syncthreads();
  if (tid < 64) {
    int v = hist[tid];
    int incl = wave_incl_scan_int(v, tid);
    offs[tid] = incl - v;
    cur[tid] = incl - v;
    if (tid == 63) offs[64] = incl;
  }
  __syncthreads();
  for (int i = tid; i < cnt; i += 256) {
    int e = rawE[i];
    int p = atomicAdd(&cur[e & 63], 1);
    srcsS[(size_t)b * BCAP + p] = e >> 6;
  }
  if (tid < 65) boffs[b * 65 + tid] = offs[tid];
}

// ------------------------- fused layer (layers 1,2) -------------------------
// Block = bucket = 64 nodes. Neighbor gather from fp8 Xq via dwordx4: 8
// lanes x 16B per 128B row -> 8 edges per wave instr. Self term: bf16 Xb
// if non-null (layer 1, exact), else fp8 Xq. MFMA 64x128 (2x2 waves,
// 32m x 64n, K=128); coalesced weight frags. Epilogue: fp8 staged in LDS
// (As region, dead after MFMA) then 2 coalesced dwordx4 stores/thread.
__global__ __launch_bounds__(256) void fused_layer(
    const unsigned short* __restrict__ Xb, const unsigned char* __restrict__ Xq,
    const int* __restrict__ bcnt,
    const int* __restrict__ srcsS, const int* __restrict__ boffs,
    const unsigned short* __restrict__ BT, const float* __restrict__ bias,
    unsigned char* __restrict__ Cq, int M) {
  __shared__ __align__(16) unsigned short As[64 * 136];
  __shared__ int srcS[BCAP];
  __shared__ int offs[65];
  const int tid = threadIdx.x;
  const int lane = tid & 63;
  const int b = blockIdx.x;
  const int blk = b * 64;
  const int cnt = bcnt[b];

  if (tid < 65) offs[tid] = boffs[b * 65 + tid];
  for (int i = tid; i < cnt; i += 256) srcS[i] = srcsS[(size_t)b * BCAP + i];
  __syncthreads();

  // ---- gather: 2 sweeps x 32 nodes; 8 lanes x 16B fp8 per row
  const int l = tid & 7, g = tid >> 3;
  const uint4* baseb = (const uint4*)Xb;  // bf16 rows: 16 x uint4 (may be null)
  const uint4* baseq = (const uint4*)Xq;  // fp8 rows:   8 x uint4
#pragma unroll
  for (int s2 = 0; s2 < 2; ++s2) {
    int nl = s2 * 32 + g;
    int node = blk + nl;
    float s[16] = {0, 0, 0, 0, 0, 0, 0, 0, 0, 0, 0, 0, 0, 0, 0, 0};
    if (node < M) {
      if (Xb) {
        add8(s, baseb[(size_t)node * 16 + l * 2]);
        add8(s + 8, baseb[(size_t)node * 16 + l * 2 + 1]);
      } else {
        addf8q(s, baseq[(size_t)node * 8 + l]);
      }
      int beg = offs[nl], c = offs[nl + 1] - beg;
      int j = 0;
      for (; j + 8 <= c; j += 8) {
        int i0 = srcS[beg + j + 0], i1 = srcS[beg + j + 1];
        int i2 = srcS[beg + j + 2], i3 = srcS[beg + j + 3];
        int i4 = srcS[beg + j + 4], i5 = srcS[beg + j + 5];
        int i6 = srcS[beg + j + 6], i7 = srcS[beg + j + 7];
        uint4 v0 = baseq[(size_t)i0 * 8 + l];
        uint4 v1 = baseq[(size_t)i1 * 8 + l];
        uint4 v2 = baseq[(size_t)i2 * 8 + l];
        uint4 v3 = baseq[(size_t)i3 * 8 + l];
        uint4 v4 = baseq[(size_t)i4 * 8 + l];
        uint4 v5 = baseq[(size_t)i5 * 8 + l];
        uint4 v6 = baseq[(size_t)i6 * 8 + l];
        uint4 v7 = baseq[(size_t)i7 * 8 + l];
        addf8q(s, v0); addf8q(s, v1); addf8q(s, v2); addf8q(s, v3);
        addf8q(s, v4); addf8q(s, v5); addf8q(s, v6); addf8q(s, v7);
      }
      if (j + 4 <= c) {
        int i0 = srcS[beg + j + 0], i1 = srcS[beg + j + 1];
        int i2 = srcS[beg + j + 2], i3 = srcS[beg + j + 3];
        uint4 v0 = baseq[(size_t)i0 * 8 + l];
        uint4 v1 = baseq[(size_t)i1 * 8 + l];
        uint4 v2 = baseq[(size_t)i2 * 8 + l];
        uint4 v3 = baseq[(size_t)i3 * 8 + l];
        addf8q(s, v0); addf8q(s, v1); addf8q(s, v2); addf8q(s, v3);
        j += 4;
      }
      if (j + 2 <= c) {
        int i0 = srcS[beg + j + 0], i1 = srcS[beg + j + 1];
        uint4 v0 = baseq[(size_t)i0 * 8 + l];
        uint4 v1 = baseq[(size_t)i1 * 8 + l];
        addf8q(s, v0); addf8q(s, v1);
        j += 2;
      }
      if (j < c) addf8q(s, baseq[(size_t)srcS[beg + j] * 8 + l]);
    }
    uint4 o0, o1;
    o0.x = pack2(s[0], s[1]);   o0.y = pack2(s[2], s[3]);
    o0.z = pack2(s[4], s[5]);   o0.w = pack2(s[6], s[7]);
    o1.x = pack2(s[8], s[9]);   o1.y = pack2(s[10], s[11]);
    o1.z = pack2(s[12], s[13]); o1.w = pack2(s[14], s[15]);
    *(uint4*)&As[nl * 136 + l * 16] = o0;
    *(uint4*)&As[nl * 136 + l * 16 + 8] = o1;
  }
  __syncthreads();

  // ---- MFMA: 4 waves 2x2; wave tile 32m x 64n; K=128; coalesced B-frags
  const int w = tid >> 6;
  const int wm = w & 1, wn = w >> 1;
  const int l15 = lane & 15, quad = lane >> 4;
  const int mb = wm * 32, nb2 = wn * 64;

  v4f acc[2][4];
#pragma unroll
  for (int mf = 0; mf < 2; ++mf)
#pragma unroll
    for (int nf = 0; nf < 4; ++nf) acc[mf][nf] = (v4f)0.f;

#pragma unroll
  for (int k0 = 0; k0 < 128; k0 += 32) {
    const int kq = k0 >> 5;
    short8 a[2], bv[4];
#pragma unroll
    for (int mf = 0; mf < 2; ++mf)
      a[mf] = *(const short8*)&As[(mb + mf * 16 + l15) * 136 + k0 + quad * 8];
#pragma unroll
    for (int nf = 0; nf < 4; ++nf)
      bv[nf] = *(const short8*)(BT + (size_t)(kq * 8 + wn * 4 + nf) * 512 + lane * 8);
#pragma unroll
    for (int mf = 0; mf < 2; ++mf)
#pragma unroll
      for (int nf = 0; nf < 4; ++nf)
        acc[mf][nf] = __builtin_amdgcn_mfma_f32_16x16x32_bf16(a[mf], bv[nf], acc[mf][nf], 0, 0, 0);
  }
  __syncthreads();  // all As reads done; reuse As as fp8 staging

  // ---- epilogue: bias+relu+fp8 into LDS, then coalesced 16B stores
  unsigned char* Cs = (unsigned char*)As;  // 64 x 128 = 8KB
#pragma unroll
  for (int mf = 0; mf < 2; ++mf)
#pragma unroll
    for (int r = 0; r < 4; ++r) {
      int row = mb + mf * 16 + quad * 4 + r;
#pragma unroll
      for (int nf = 0; nf < 4; ++nf) {
        int col = nb2 + nf * 16 + l15;
        Cs[row * 128 + col] = f2fp8(fmaxf(acc[mf][nf][r] + bias[col], 0.f));
      }
    }
  __syncthreads();
  uint4* dst4 = (uint4*)(Cq + (size_t)blk * 128);
  const uint4* s4 = (const uint4*)Cs;
  if (blk + 64 <= M) {
    dst4[tid] = s4[tid];
    dst4[tid + 256] = s4[tid + 256];
  } else {
    for (int c2 = tid; c2 < 512; c2 += 256)
      if (blk + (c2 >> 3) < M) dst4[c2] = s4[c2];
  }
}

// ------------------------- fused layer 3 + MLP head -------------------------
// fp8-self gather + layer-3 MFMA, then head in LDS (34KB union). All weight
// B-fragments coalesced.  (unchanged from r13 -- control)
__global__ __launch_bounds__(256) void fused_l3_head(
    const unsigned char* __restrict__ Xq,
    const int* __restrict__ bcnt,
    const int* __restrict__ srcsS, const int* __restrict__ boffs,
    const unsigned short* __restrict__ W2T, const float* __restrict__ b2,
    const unsigned short* __restrict__ Wm1T, const float* __restrict__ bm1,
    const unsigned short* __restrict__ Wm2T, const float* __restrict__ bm2,
    float* __restrict__ out, int M, int NOUT) {
  __shared__ __align__(16) unsigned char lds[64 * 264 * 2];  // Hs 33.8KB
  unsigned short* As = (unsigned short*)lds;                 // 17.4KB
  int* srcS = (int*)(lds + 64 * 136 * 2);                    // 4KB after As
  unsigned short* Hs = (unsigned short*)lds;                 // aliases both
  __shared__ int offs[65];
  const int tid = threadIdx.x;
  const int lane = tid & 63;
  const int b = blockIdx.x;
  const int blk = b * 64;
  const int cnt = bcnt[b];

  if (tid < 65) offs[tid] = boffs[b * 65 + tid];
  for (int i = tid; i < cnt; i += 256) srcS[i] = srcsS[(size_t)b * BCAP + i];
  __syncthreads();

  // ---- gather (self from fp8 Xq)
  const int l = tid & 7, g = tid >> 3;
  const uint4* baseq = (const uint4*)Xq;
#pragma unroll
  for (int s2 = 0; s2 < 2; ++s2) {
    int nl = s2 * 32 + g;
    int node = blk + nl;
    float s[16] = {0, 0, 0, 0, 0, 0, 0, 0, 0, 0, 0, 0, 0, 0, 0, 0};
    if (node < M) {
      addf8q(s, baseq[(size_t)node * 8 + l]);
      int beg = offs[nl], c = offs[nl + 1] - beg;
      int j = 0;
      for (; j + 8 <= c; j += 8) {
        int i0 = srcS[beg + j + 0], i1 = srcS[beg + j + 1];
        int i2 = srcS[beg + j + 2], i3 = srcS[beg + j + 3];
        int i4 = srcS[beg + j + 4], i5 = srcS[beg + j + 5];
        int i6 = srcS[beg + j + 6], i7 = srcS[beg + j + 7];
        uint4 v0 = baseq[(size_t)i0 * 8 + l];
        uint4 v1 = baseq[(size_t)i1 * 8 + l];
        uint4 v2 = baseq[(size_t)i2 * 8 + l];
        uint4 v3 = baseq[(size_t)i3 * 8 + l];
        uint4 v4 = baseq[(size_t)i4 * 8 + l];
        uint4 v5 = baseq[(size_t)i5 * 8 + l];
        uint4 v6 = baseq[(size_t)i6 * 8 + l];
        uint4 v7 = baseq[(size_t)i7 * 8 + l];
        addf8q(s, v0); addf8q(s, v1); addf8q(s, v2); addf8q(s, v3);
        addf8q(s, v4); addf8q(s, v5); addf8q(s, v6); addf8q(s, v7);
      }
      if (j + 4 <= c) {
        int i0 = srcS[beg + j + 0], i1 = srcS[beg + j + 1];
        int i2 = srcS[beg + j + 2], i3 = srcS[beg + j + 3];
        uint4 v0 = baseq[(size_t)i0 * 8 + l];
        uint4 v1 = baseq[(size_t)i1 * 8 + l];
        uint4 v2 = baseq[(size_t)i2 * 8 + l];
        uint4 v3 = baseq[(size_t)i3 * 8 + l];
        addf8q(s, v0); addf8q(s, v1); addf8q(s, v2); addf8q(s, v3);
        j += 4;
      }
      if (j + 2 <= c) {
        int i0 = srcS[beg + j + 0], i1 = srcS[beg + j + 1];
        uint4 v0 = baseq[(size_t)i0 * 8 + l];
        uint4 v1 = baseq[(size_t)i1 * 8 + l];
        addf8q(s, v0); addf8q(s, v1);
        j += 2;
      }
      if (j < c) addf8q(s, baseq[(size_t)srcS[beg + j] * 8 + l]);
    }
    uint4 o0, o1;
    o0.x = pack2(s[0], s[1]);   o0.y = pack2(s[2], s[3]);
    o0.z = pack2(s[4], s[5]);   o0.w = pack2(s[6], s[7]);
    o1.x = pack2(s[8], s[9]);   o1.y = pack2(s[10], s[11]);
    o1.z = pack2(s[12], s[13]); o1.w = pack2(s[14], s[15]);
    *(uint4*)&As[nl * 136 + l * 16] = o0;
    *(uint4*)&As[nl * 136 + l * 16 + 8] = o1;
  }
  __syncthreads();

  // ---- layer-3 MFMA: 64x128, K=128; coalesced W2 frags
  const int w = tid >> 6;
  const int wm = w & 1, wn = w >> 1;
  const int l15 = lane & 15, quad = lane >> 4;
  const int mb = wm * 32, nb2 = wn * 64;

  v4f acc[2][4];
#pragma unroll
  for (int mf = 0; mf < 2; ++mf)
#pragma unroll
    for (int nf = 0; nf < 4; ++nf) acc[mf][nf] = (v4f)0.f;

#pragma unroll
  for (int k0 = 0; k0 < 128; k0 += 32) {
    const int kq = k0 >> 5;
    short8 a[2], bv[4];
#pragma unroll
    for (int mf = 0; mf < 2; ++mf)
      a[mf] = *(const short8*)&As[(mb + mf * 16 + l15) * 136 + k0 + quad * 8];
#pragma unroll
    for (int nf = 0; nf < 4; ++nf)
      bv[nf] = *(const short8*)(W2T + (size_t)(kq * 8 + wn * 4 + nf) * 512 + lane * 8);
#pragma unroll
    for (int mf = 0; mf < 2; ++mf)
#pragma unroll
      for (int nf = 0; nf < 4; ++nf)
        acc[mf][nf] = __builtin_amdgcn_mfma_f32_16x16x32_bf16(a[mf], bv[nf], acc[mf][nf], 0, 0, 0);
  }
  __syncthreads();  // all As reads done before rewrite

  // t = relu(acc + b2) -> back into As (local rows 0..63, cols 0..127)
#pragma unroll
  for (int mf = 0; mf < 2; ++mf)
#pragma unroll
    for (int r = 0; r < 4; ++r) {
      int row = mb + mf * 16 + quad * 4 + r;
#pragma unroll
      for (int nf = 0; nf < 4; ++nf) {
        int col = nb2 + nf * 16 + l15;
        As[row * 136 + col] = f2bf(fmaxf(acc[mf][nf][r] + b2[col], 0.f));
      }
    }
  __syncthreads();

  // ---- head phase A: Hm = relu(t @ Wm1 + bm1), 64x256, K=128; coalesced
  const int nbH = wn * 128;
  v4f acc2[2][8];
#pragma unroll
  for (int mf = 0; mf < 2; ++mf)
#pragma unroll
    for (int nf = 0; nf < 8; ++nf) acc2[mf][nf] = (v4f)0.f;

#pragma unroll
  for (int k0 = 0; k0 < 128; k0 += 32) {
    const int kq = k0 >> 5;
    short8 a[2];
#pragma unroll
    for (int mf = 0; mf < 2; ++mf)
      a[mf] = *(const short8*)&As[(mb + mf * 16 + l15) * 136 + k0 + quad * 8];
#pragma unroll
    for (int nf = 0; nf < 8; ++nf) {
      short8 bb = *(const short8*)(Wm1T + (size_t)(kq * 16 + wn * 8 + nf) * 512 + lane * 8);
#pragma unroll
      for (int mf = 0; mf < 2; ++mf)
        acc2[mf][nf] = __builtin_amdgcn_mfma_f32_16x16x32_bf16(a[mf], bb, acc2[mf][nf], 0, 0, 0);
    }
  }
  __syncthreads();  // As reads done; Hs may overwrite

#pragma unroll
  for (int mf = 0; mf < 2; ++mf)
#pragma unroll
    for (int r = 0; r < 4; ++r) {
      int row = mb + mf * 16 + quad * 4 + r;
#pragma unroll
      for (int nf = 0; nf < 8; ++nf) {
        int col = nbH + nf * 16 + l15;
        Hs[row * 264 + col] = f2bf(fmaxf(acc2[mf][nf][r] + bm1[col], 0.f));
      }
    }
  __syncthreads();

  // ---- head phase B: out = Hs @ Wm2 + bm2; 64x16, K=256; coalesced frags
  const int rowl = w * 16 + l15;
  v4f acc3 = (v4f)0.f;
#pragma unroll
  for (int k0 = 0; k0 < 256; k0 += 32)
    acc3 = __builtin_amdgcn_mfma_f32_16x16x32_bf16(
        *(const short8*)&Hs[rowl * 264 + k0 + quad * 8],
        *(const short8*)(Wm2T + (size_t)(k0 >> 5) * 512 + lane * 8), acc3, 0, 0, 0);
  float bb = (l15 < NOUT) ? bm2[l15] : 0.f;
#pragma unroll
  for (int r = 0; r < 4; ++r) {
    int grow = blk + w * 16 + quad * 4 + r;
    if (grow < M && l15 < NOUT) out[(size_t)grow * NOUT + l15] = acc3[r] + bb;
  }
}

// ---------------------------------------------------------------------------

extern "C" void kernel_launch(void* const* d_in, const int* in_sizes, int n_in,
                              void* d_out, int out_size, void* d_ws, size_t ws_size,
                              hipStream_t stream) {
  const float* x   = (const float*)d_in[0];
  const int*   ei  = (const int*)d_in[1];
  const float* W0  = (const float*)d_in[2];
  const float* b0  = (const float*)d_in[3];
  const float* W1  = (const float*)d_in[4];
  const float* b1  = (const float*)d_in[5];
  const float* W2  = (const float*)d_in[6];
  const float* b2  = (const float*)d_in[7];
  const float* Wm1 = (const float*)d_in[8];
  const float* bm1 = (const float*)d_in[9];
  const float* Wm2 = (const float*)d_in[10];
  const float* bm2 = (const float*)d_in[11];
  float* out = (float*)d_out;

  const int D = 128;
  const int N = in_sizes[0] / D;   // 50000
  const int E = in_sizes[1] / 2;   // 600000
  const int L = in_sizes[11];      // 10
  const int nb = (N + 63) / 64;    // 782 buckets == layer tiles

  const int* srcv = ei;
  const int* dstv = ei + E;

  char* ws = (char*)d_ws;
  size_t off = 0;
  auto alloc = [&](size_t bytes) -> void* {
    void* p = ws + off;
    off = (off + bytes + 255) & ~(size_t)255;
    return p;
  };
  int* bcnt    = (int*)alloc((size_t)MAXB * 4);
  int* bucketA = (int*)alloc((size_t)nb * BCAP * 4);
  int* srcsS   = (int*)alloc((size_t)nb * BCAP * 4);
  int* boffs   = (int*)alloc((size_t)nb * 65 * 4);
  unsigned short* xb   = (unsigned short*)alloc((size_t)N * 128 * 2);
  unsigned char*  xq   = (unsigned char*)alloc((size_t)N * 128);
  unsigned char*  h1q  = (unsigned char*)alloc((size_t)N * 128);
  unsigned char*  h2q  = (unsigned char*)alloc((size_t)N * 128);
  unsigned short* W0T  = (unsigned short*)alloc(128 * 128 * 2);
  unsigned short* W1T  = (unsigned short*)alloc(128 * 128 * 2);
  unsigned short* W2T  = (unsigned short*)alloc(128 * 128 * 2);
  unsigned short* Wm1T = (unsigned short*)alloc(256 * 128 * 2);
  unsigned short* Wm2T = (unsigned short*)alloc(16 * 256 * 2);
  (void)ws_size; (void)n_in; (void)out_size;

  const int tpb = 256;
  int n8 = N * 16;
  const int PB = (n8 + tpb - 1) / tpb;         // 3125 prep blocks
  int per = (E + NBIN - 1) / NBIN;             // 1172 edges per bin block

  hipMemsetAsync(bcnt, 0, (size_t)MAXB * 4, stream);
  prep_bin<<<dim3(PB + NBIN), dim3(tpb), 0, stream>>>(
      W0, W1, W2, Wm1, Wm2, W0T, W1T, W2T, Wm1T, Wm2T,
      x, xb, xq, n8, PB, srcv, dstv, E, per, bcnt, bucketA, nb);
  sort_buckets<<<dim3(nb), dim3(tpb), 0, stream>>>(bcnt, bucketA, srcsS, boffs);

  dim3 lgrid(nb);
  fused_layer<<<lgrid, dim3(tpb), 0, stream>>>(
      xb, xq, bcnt, srcsS, boffs, W0T, b0, h1q, N);          // L1: self bf16
  fused_layer<<<lgrid, dim3(tpb), 0, stream>>>(
      nullptr, h1q, bcnt, srcsS, boffs, W1T, b1, h2q, N);    // L2: self fp8
  fused_l3_head<<<lgrid, dim3(tpb), 0, stream>>>(
      h2q, bcnt, srcsS, boffs, W2T, b2, Wm1T, bm1, Wm2T, bm2, out, N, L);
}

// Round 9
// 198.612 us; speedup vs baseline: 1.2701x; 1.0124x over previous
//
#include <hip/hip_runtime.h>

// ---------------------------------------------------------------------------
// GIN: 3 x (bucket gather-sum + (x+agg)@W + b, relu) + MLP head, bf16 MFMA.
// r15: sort_buckets dispatch merged into layer 1 (fused_sort_layer): each
//     block stages raw bucketA[b] -> LDS, counting-sorts in LDS (and writes
//     srcsS/boffs for FL2/l3), then gathers from the LDS-resident list.
//     Saves a dispatch + gap + bucketA re-read. FL2/l3 unchanged (controls).
//     Law (r6-r14): scattered-LOAD wave-instrs cost ~188cyc/CU each,
//     invariant to bytes/segments/waves; stores are free (r14 null).
//     Keeps: frag-major weights (r13), fp8-only hidden state (r11/r12),
//     dwordx4 fp8 gather = 8 edges/instr (r9 floor), LDS epilogue (r14).
//     4 dispatches + memset: prep_bin, fused_sort_layer, fused_layer,
//     fused_l3_head.
// ---------------------------------------------------------------------------

typedef short short8 __attribute__((ext_vector_type(8)));
typedef float v4f __attribute__((ext_vector_type(4)));
typedef float v2f __attribute__((ext_vector_type(2)));

#define BCAP 1024   // bucket capacity: avg 768 edges, +9 sigma head-room
#define MAXB 1024   // >= nbuckets (782)
#define NBIN 512    // edge-binning blocks

__device__ inline unsigned short f2bf(float f) {
  union { float f; unsigned int u; } c; c.f = f;
  unsigned int u = c.u;
  return (unsigned short)((u + 0x7fffu + ((u >> 16) & 1u)) >> 16);  // RNE
}
__device__ inline float bfbits2f(unsigned int hi) {
  union { unsigned int u; float f; } c; c.u = hi; return c.f;
}
__device__ inline unsigned int pack2(float a, float b) {
  return (unsigned int)f2bf(a) | ((unsigned int)f2bf(b) << 16);
}
__device__ inline void add8(float* s, uint4 v) {
  s[0] += bfbits2f(v.x << 16); s[1] += bfbits2f(v.x & 0xffff0000u);
  s[2] += bfbits2f(v.y << 16); s[3] += bfbits2f(v.y & 0xffff0000u);
  s[4] += bfbits2f(v.z << 16); s[5] += bfbits2f(v.z & 0xffff0000u);
  s[6] += bfbits2f(v.w << 16); s[7] += bfbits2f(v.w & 0xffff0000u);
}
// decode 16 fp8 (e4m3, HW format) and accumulate into s[0..15]
__device__ inline void addf8q(float* s, uint4 v) {
  v2f p;
  p = __builtin_amdgcn_cvt_pk_f32_fp8(v.x, false); s[0]  += p.x; s[1]  += p.y;
  p = __builtin_amdgcn_cvt_pk_f32_fp8(v.x, true);  s[2]  += p.x; s[3]  += p.y;
  p = __builtin_amdgcn_cvt_pk_f32_fp8(v.y, false); s[4]  += p.x; s[5]  += p.y;
  p = __builtin_amdgcn_cvt_pk_f32_fp8(v.y, true);  s[6]  += p.x; s[7]  += p.y;
  p = __builtin_amdgcn_cvt_pk_f32_fp8(v.z, false); s[8]  += p.x; s[9]  += p.y;
  p = __builtin_amdgcn_cvt_pk_f32_fp8(v.z, true);  s[10] += p.x; s[11] += p.y;
  p = __builtin_amdgcn_cvt_pk_f32_fp8(v.w, false); s[12] += p.x; s[13] += p.y;
  p = __builtin_amdgcn_cvt_pk_f32_fp8(v.w, true);  s[14] += p.x; s[15] += p.y;
}
__device__ inline unsigned char f2fp8(float v) {
  return (unsigned char)(__builtin_amdgcn_cvt_pk_fp8_f32(v, v, 0, false) & 0xff);
}
__device__ inline int wave_incl_scan_int(int v, int lane) {
#pragma unroll
  for (int off = 1; off < 64; off <<= 1) {
    int t = __shfl_up(v, off, 64);
    if (lane >= off) v += t;
  }
  return v;
}

// ------------- merged prep (weights + x->bf16/fp8) & edge binning -----------
// Blocks [0,PB): prep.  Blocks [PB,PB+NBIN): bin edges into 64-node buckets.
// entry = (src << 6) | (dst & 63); bucket = dst >> 6.  bcnt pre-zeroed.
__global__ __launch_bounds__(256) void prep_bin(
    const float* __restrict__ W0, const float* __restrict__ W1, const float* __restrict__ W2,
    const float* __restrict__ Wm1, const float* __restrict__ Wm2,
    unsigned short* __restrict__ W0T, unsigned short* __restrict__ W1T,
    unsigned short* __restrict__ W2T, unsigned short* __restrict__ Wm1T,
    unsigned short* __restrict__ Wm2T,
    const float* __restrict__ x, unsigned short* __restrict__ xb,
    unsigned char* __restrict__ xq, int n8, int PB,
    const int* __restrict__ src, const int* __restrict__ dst, int E, int per,
    int* __restrict__ bcnt, int* __restrict__ bucketA, int nbuckets) {
  __shared__ int hist[MAXB];
  __shared__ int base[MAXB];
  const int tid = threadIdx.x;
  if (blockIdx.x < PB) {
    // ---- prep branch
    int i = blockIdx.x * 256 + tid;
    if (i < n8) {
      const float4* p = (const float4*)x;
      float4 a = p[2 * (size_t)i], b = p[2 * (size_t)i + 1];
      uint4 o;
      o.x = pack2(a.x, a.y); o.y = pack2(a.z, a.w);
      o.z = pack2(b.x, b.y); o.w = pack2(b.z, b.w);
      ((uint4*)xb)[i] = o;
      unsigned int lo = 0, hi = 0;
      lo = __builtin_amdgcn_cvt_pk_fp8_f32(a.x, a.y, lo, false);
      lo = __builtin_amdgcn_cvt_pk_fp8_f32(a.z, a.w, lo, true);
      hi = __builtin_amdgcn_cvt_pk_fp8_f32(b.x, b.y, hi, false);
      hi = __builtin_amdgcn_cvt_pk_fp8_f32(b.z, b.w, hi, true);
      uint2 q; q.x = lo; q.y = hi;
      ((uint2*)xq)[i] = q;
    }
    if (i < 49152) {                       // 3 x [128,128]: frag = kq*8 + nfr
      int w = i / 16384, r = i % 16384;
      int frag = r >> 9, l = (r >> 3) & 63, j = r & 7;
      int kq = frag >> 3, nfr = frag & 7;
      int nn = nfr * 16 + (l & 15);
      int k  = kq * 32 + (l >> 4) * 8 + j;
      const float* W = (w == 0) ? W0 : (w == 1) ? W1 : W2;
      unsigned short* O = (w == 0) ? W0T : (w == 1) ? W1T : W2T;
      O[r] = f2bf(W[k * 128 + nn]);
    } else if (i < 49152 + 32768) {        // Wm1 [128,256]: frag = kq*16 + nfr
      int r = i - 49152;
      int frag = r >> 9, l = (r >> 3) & 63, j = r & 7;
      int kq = frag >> 4, nfr = frag & 15;
      int nn = nfr * 16 + (l & 15);
      int k  = kq * 32 + (l >> 4) * 8 + j;
      Wm1T[r] = f2bf(Wm1[k * 256 + nn]);
    } else if (i < 49152 + 32768 + 4096) { // Wm2 [256,10]: frag = kq, pad 16
      int r = i - 49152 - 32768;
      int kq = r >> 9, l = (r >> 3) & 63, j = r & 7;
      int nn = l & 15;
      int k  = kq * 32 + (l >> 4) * 8 + j;
      Wm2T[r] = (nn < 10) ? f2bf(Wm2[k * 10 + nn]) : (unsigned short)0;
    }
  } else {
    // ---- bin branch
    const int bb = blockIdx.x - PB;
    const int e0 = bb * per;
    const int e1 = (e0 + per < E) ? e0 + per : E;
    for (int j = tid; j < nbuckets; j += 256) hist[j] = 0;
    __syncthreads();
    for (int i = e0 + tid; i < e1; i += 256) atomicAdd(&hist[dst[i] >> 6], 1);
    __syncthreads();
    for (int j = tid; j < nbuckets; j += 256) {
      int h = hist[j];
      base[j] = h ? atomicAdd(&bcnt[j], h) : 0;
    }
    __syncthreads();
    for (int i = e0 + tid; i < e1; i += 256) {
      int d = dst[i], s = src[i];
      int b = d >> 6;
      int r = atomicAdd(&base[b], 1);
      bucketA[(size_t)b * BCAP + r] = (s << 6) | (d & 63);
    }
  }
}

// ------------------- fused sort + layer 1 (self from bf16 xb) ---------------
// Block = bucket = 64 nodes. Phase 0: stage raw bucketA[b] -> LDS, counting
// sort in LDS (srcS sorted by local node, offs prefix); also write srcsS +
// boffs to global for layers 2/3. Phase 1: gather from LDS list (fp8 Xq,
// dwordx4, 8 edges/instr). Phase 2: MFMA 64x128 + LDS-staged fp8 epilogue.
__global__ __launch_bounds__(256) void fused_sort_layer(
    const unsigned short* __restrict__ Xb, const unsigned char* __restrict__ Xq,
    const int* __restrict__ bcnt, const int* __restrict__ bucketA,
    int* __restrict__ srcsS, int* __restrict__ boffs,
    const unsigned short* __restrict__ BT, const float* __restrict__ bias,
    unsigned char* __restrict__ Cq, int M) {
  __shared__ __align__(16) unsigned short As[64 * 136];
  __shared__ int rawE[BCAP];
  __shared__ int srcS[BCAP];
  __shared__ int hist[64], cur[64], offs[65];
  const int tid = threadIdx.x;
  const int lane = tid & 63;
  const int b = blockIdx.x;
  const int blk = b * 64;
  const int cnt = bcnt[b];

  // ---- phase 0: LDS counting sort of this bucket
  for (int i = tid; i < cnt; i += 256) rawE[i] = bucketA[(size_t)b * BCAP + i];
  if (tid < 64) hist[tid] = 0;
  __syncthreads();
  for (int i = tid; i < cnt; i += 256) atomicAdd(&hist[rawE[i] & 63], 1);
  __syncthreads();
  if (tid < 64) {
    int v = hist[tid];
    int incl = wave_incl_scan_int(v, tid);
    offs[tid] = incl - v;
    cur[tid] = incl - v;
    if (tid == 63) offs[64] = incl;
  }
  __syncthreads();
  for (int i = tid; i < cnt; i += 256) {
    int e = rawE[i];
    int p = atomicAdd(&cur[e & 63], 1);
    int sv = e >> 6;
    srcS[p] = sv;
    srcsS[(size_t)b * BCAP + p] = sv;   // for layers 2/3
  }
  if (tid < 65) boffs[b * 65 + tid] = offs[tid];
  __syncthreads();

  // ---- phase 1: gather (2 sweeps x 32 nodes; 8 lanes x 16B fp8 per row)
  const int l = tid & 7, g = tid >> 3;
  const uint4* baseb = (const uint4*)Xb;  // bf16 rows: 16 x uint4
  const uint4* baseq = (const uint4*)Xq;  // fp8 rows:   8 x uint4
#pragma unroll
  for (int s2 = 0; s2 < 2; ++s2) {
    int nl = s2 * 32 + g;
    int node = blk + nl;
    float s[16] = {0, 0, 0, 0, 0, 0, 0, 0, 0, 0, 0, 0, 0, 0, 0, 0};
    if (node < M) {
      add8(s, baseb[(size_t)node * 16 + l * 2]);
      add8(s + 8, baseb[(size_t)node * 16 + l * 2 + 1]);
      int beg = offs[nl], c = offs[nl + 1] - beg;
      int j = 0;
      for (; j + 8 <= c; j += 8) {
        int i0 = srcS[beg + j + 0], i1 = srcS[beg + j + 1];
        int i2 = srcS[beg + j + 2], i3 = srcS[beg + j + 3];
        int i4 = srcS[beg + j + 4], i5 = srcS[beg + j + 5];
        int i6 = srcS[beg + j + 6], i7 = srcS[beg + j + 7];
        uint4 v0 = baseq[(size_t)i0 * 8 + l];
        uint4 v1 = baseq[(size_t)i1 * 8 + l];
        uint4 v2 = baseq[(size_t)i2 * 8 + l];
        uint4 v3 = baseq[(size_t)i3 * 8 + l];
        uint4 v4 = baseq[(size_t)i4 * 8 + l];
        uint4 v5 = baseq[(size_t)i5 * 8 + l];
        uint4 v6 = baseq[(size_t)i6 * 8 + l];
        uint4 v7 = baseq[(size_t)i7 * 8 + l];
        addf8q(s, v0); addf8q(s, v1); addf8q(s, v2); addf8q(s, v3);
        addf8q(s, v4); addf8q(s, v5); addf8q(s, v6); addf8q(s, v7);
      }
      if (j + 4 <= c) {
        int i0 = srcS[beg + j + 0], i1 = srcS[beg + j + 1];
        int i2 = srcS[beg + j + 2], i3 = srcS[beg + j + 3];
        uint4 v0 = baseq[(size_t)i0 * 8 + l];
        uint4 v1 = baseq[(size_t)i1 * 8 + l];
        uint4 v2 = baseq[(size_t)i2 * 8 + l];
        uint4 v3 = baseq[(size_t)i3 * 8 + l];
        addf8q(s, v0); addf8q(s, v1); addf8q(s, v2); addf8q(s, v3);
        j += 4;
      }
      if (j + 2 <= c) {
        int i0 = srcS[beg + j + 0], i1 = srcS[beg + j + 1];
        uint4 v0 = baseq[(size_t)i0 * 8 + l];
        uint4 v1 = baseq[(size_t)i1 * 8 + l];
        addf8q(s, v0); addf8q(s, v1);
        j += 2;
      }
      if (j < c) addf8q(s, baseq[(size_t)srcS[beg + j] * 8 + l]);
    }
    uint4 o0, o1;
    o0.x = pack2(s[0], s[1]);   o0.y = pack2(s[2], s[3]);
    o0.z = pack2(s[4], s[5]);   o0.w = pack2(s[6], s[7]);
    o1.x = pack2(s[8], s[9]);   o1.y = pack2(s[10], s[11]);
    o1.z = pack2(s[12], s[13]); o1.w = pack2(s[14], s[15]);
    *(uint4*)&As[nl * 136 + l * 16] = o0;
    *(uint4*)&As[nl * 136 + l * 16 + 8] = o1;
  }
  __syncthreads();

  // ---- phase 2: MFMA 4 waves 2x2; wave tile 32m x 64n; K=128
  const int w = tid >> 6;
  const int wm = w & 1, wn = w >> 1;
  const int l15 = lane & 15, quad = lane >> 4;
  const int mb = wm * 32, nb2 = wn * 64;

  v4f acc[2][4];
#pragma unroll
  for (int mf = 0; mf < 2; ++mf)
#pragma unroll
    for (int nf = 0; nf < 4; ++nf) acc[mf][nf] = (v4f)0.f;

#pragma unroll
  for (int k0 = 0; k0 < 128; k0 += 32) {
    const int kq = k0 >> 5;
    short8 a[2], bv[4];
#pragma unroll
    for (int mf = 0; mf < 2; ++mf)
      a[mf] = *(const short8*)&As[(mb + mf * 16 + l15) * 136 + k0 + quad * 8];
#pragma unroll
    for (int nf = 0; nf < 4; ++nf)
      bv[nf] = *(const short8*)(BT + (size_t)(kq * 8 + wn * 4 + nf) * 512 + lane * 8);
#pragma unroll
    for (int mf = 0; mf < 2; ++mf)
#pragma unroll
      for (int nf = 0; nf < 4; ++nf)
        acc[mf][nf] = __builtin_amdgcn_mfma_f32_16x16x32_bf16(a[mf], bv[nf], acc[mf][nf], 0, 0, 0);
  }
  __syncthreads();  // all As reads done; reuse As as fp8 staging

  unsigned char* Cs = (unsigned char*)As;  // 64 x 128 = 8KB
#pragma unroll
  for (int mf = 0; mf < 2; ++mf)
#pragma unroll
    for (int r = 0; r < 4; ++r) {
      int row = mb + mf * 16 + quad * 4 + r;
#pragma unroll
      for (int nf = 0; nf < 4; ++nf) {
        int col = nb2 + nf * 16 + l15;
        Cs[row * 128 + col] = f2fp8(fmaxf(acc[mf][nf][r] + bias[col], 0.f));
      }
    }
  __syncthreads();
  uint4* dst4 = (uint4*)(Cq + (size_t)blk * 128);
  const uint4* s4 = (const uint4*)Cs;
  if (blk + 64 <= M) {
    dst4[tid] = s4[tid];
    dst4[tid + 256] = s4[tid + 256];
  } else {
    for (int c2 = tid; c2 < 512; c2 += 256)
      if (blk + (c2 >> 3) < M) dst4[c2] = s4[c2];
  }
}

// ------------------------- fused layer (layer 2) ----------------------------
// Same as r14 fused_layer, fp8 self (Xb unused -> dropped).
__global__ __launch_bounds__(256) void fused_layer(
    const unsigned char* __restrict__ Xq,
    const int* __restrict__ bcnt,
    const int* __restrict__ srcsS, const int* __restrict__ boffs,
    const unsigned short* __restrict__ BT, const float* __restrict__ bias,
    unsigned char* __restrict__ Cq, int M) {
  __shared__ __align__(16) unsigned short As[64 * 136];
  __shared__ int srcS[BCAP];
  __shared__ int offs[65];
  const int tid = threadIdx.x;
  const int lane = tid & 63;
  const int b = blockIdx.x;
  const int blk = b * 64;
  const int cnt = bcnt[b];

  if (tid < 65) offs[tid] = boffs[b * 65 + tid];
  for (int i = tid; i < cnt; i += 256) srcS[i] = srcsS[(size_t)b * BCAP + i];
  __syncthreads();

  const int l = tid & 7, g = tid >> 3;
  const uint4* baseq = (const uint4*)Xq;
#pragma unroll
  for (int s2 = 0; s2 < 2; ++s2) {
    int nl = s2 * 32 + g;
    int node = blk + nl;
    float s[16] = {0, 0, 0, 0, 0, 0, 0, 0, 0, 0, 0, 0, 0, 0, 0, 0};
    if (node < M) {
      addf8q(s, baseq[(size_t)node * 8 + l]);
      int beg = offs[nl], c = offs[nl + 1] - beg;
      int j = 0;
      for (; j + 8 <= c; j += 8) {
        int i0 = srcS[beg + j + 0], i1 = srcS[beg + j + 1];
        int i2 = srcS[beg + j + 2], i3 = srcS[beg + j + 3];
        int i4 = srcS[beg + j + 4], i5 = srcS[beg + j + 5];
        int i6 = srcS[beg + j + 6], i7 = srcS[beg + j + 7];
        uint4 v0 = baseq[(size_t)i0 * 8 + l];
        uint4 v1 = baseq[(size_t)i1 * 8 + l];
        uint4 v2 = baseq[(size_t)i2 * 8 + l];
        uint4 v3 = baseq[(size_t)i3 * 8 + l];
        uint4 v4 = baseq[(size_t)i4 * 8 + l];
        uint4 v5 = baseq[(size_t)i5 * 8 + l];
        uint4 v6 = baseq[(size_t)i6 * 8 + l];
        uint4 v7 = baseq[(size_t)i7 * 8 + l];
        addf8q(s, v0); addf8q(s, v1); addf8q(s, v2); addf8q(s, v3);
        addf8q(s, v4); addf8q(s, v5); addf8q(s, v6); addf8q(s, v7);
      }
      if (j + 4 <= c) {
        int i0 = srcS[beg + j + 0], i1 = srcS[beg + j + 1];
        int i2 = srcS[beg + j + 2], i3 = srcS[beg + j + 3];
        uint4 v0 = baseq[(size_t)i0 * 8 + l];
        uint4 v1 = baseq[(size_t)i1 * 8 + l];
        uint4 v2 = baseq[(size_t)i2 * 8 + l];
        uint4 v3 = baseq[(size_t)i3 * 8 + l];
        addf8q(s, v0); addf8q(s, v1); addf8q(s, v2); addf8q(s, v3);
        j += 4;
      }
      if (j + 2 <= c) {
        int i0 = srcS[beg + j + 0], i1 = srcS[beg + j + 1];
        uint4 v0 = baseq[(size_t)i0 * 8 + l];
        uint4 v1 = baseq[(size_t)i1 * 8 + l];
        addf8q(s, v0); addf8q(s, v1);
        j += 2;
      }
      if (j < c) addf8q(s, baseq[(size_t)srcS[beg + j] * 8 + l]);
    }
    uint4 o0, o1;
    o0.x = pack2(s[0], s[1]);   o0.y = pack2(s[2], s[3]);
    o0.z = pack2(s[4], s[5]);   o0.w = pack2(s[6], s[7]);
    o1.x = pack2(s[8], s[9]);   o1.y = pack2(s[10], s[11]);
    o1.z = pack2(s[12], s[13]); o1.w = pack2(s[14], s[15]);
    *(uint4*)&As[nl * 136 + l * 16] = o0;
    *(uint4*)&As[nl * 136 + l * 16 + 8] = o1;
  }
  __syncthreads();

  const int w = tid >> 6;
  const int wm = w & 1, wn = w >> 1;
  const int l15 = lane & 15, quad = lane >> 4;
  const int mb = wm * 32, nb2 = wn * 64;

  v4f acc[2][4];
#pragma unroll
  for (int mf = 0; mf < 2; ++mf)
#pragma unroll
    for (int nf = 0; nf < 4; ++nf) acc[mf][nf] = (v4f)0.f;

#pragma unroll
  for (int k0 = 0; k0 < 128; k0 += 32) {
    const int kq = k0 >> 5;
    short8 a[2], bv[4];
#pragma unroll
    for (int mf = 0; mf < 2; ++mf)
      a[mf] = *(const short8*)&As[(mb + mf * 16 + l15) * 136 + k0 + quad * 8];
#pragma unroll
    for (int nf = 0; nf < 4; ++nf)
      bv[nf] = *(const short8*)(BT + (size_t)(kq * 8 + wn * 4 + nf) * 512 + lane * 8);
#pragma unroll
    for (int mf = 0; mf < 2; ++mf)
#pragma unroll
      for (int nf = 0; nf < 4; ++nf)
        acc[mf][nf] = __builtin_amdgcn_mfma_f32_16x16x32_bf16(a[mf], bv[nf], acc[mf][nf], 0, 0, 0);
  }
  __syncthreads();  // all As reads done; reuse As as fp8 staging

  unsigned char* Cs = (unsigned char*)As;  // 64 x 128 = 8KB
#pragma unroll
  for (int mf = 0; mf < 2; ++mf)
#pragma unroll
    for (int r = 0; r < 4; ++r) {
      int row = mb + mf * 16 + quad * 4 + r;
#pragma unroll
      for (int nf = 0; nf < 4; ++nf) {
        int col = nb2 + nf * 16 + l15;
        Cs[row * 128 + col] = f2fp8(fmaxf(acc[mf][nf][r] + bias[col], 0.f));
      }
    }
  __syncthreads();
  uint4* dst4 = (uint4*)(Cq + (size_t)blk * 128);
  const uint4* s4 = (const uint4*)Cs;
  if (blk + 64 <= M) {
    dst4[tid] = s4[tid];
    dst4[tid + 256] = s4[tid + 256];
  } else {
    for (int c2 = tid; c2 < 512; c2 += 256)
      if (blk + (c2 >> 3) < M) dst4[c2] = s4[c2];
  }
}

// ------------------------- fused layer 3 + MLP head -------------------------
// fp8-self gather + layer-3 MFMA, then head in LDS (34KB union). Unchanged
// from r13/r14 (control).
__global__ __launch_bounds__(256) void fused_l3_head(
    const unsigned char* __restrict__ Xq,
    const int* __restrict__ bcnt,
    const int* __restrict__ srcsS, const int* __restrict__ boffs,
    const unsigned short* __restrict__ W2T, const float* __restrict__ b2,
    const unsigned short* __restrict__ Wm1T, const float* __restrict__ bm1,
    const unsigned short* __restrict__ Wm2T, const float* __restrict__ bm2,
    float* __restrict__ out, int M, int NOUT) {
  __shared__ __align__(16) unsigned char lds[64 * 264 * 2];  // Hs 33.8KB
  unsigned short* As = (unsigned short*)lds;                 // 17.4KB
  int* srcS = (int*)(lds + 64 * 136 * 2);                    // 4KB after As
  unsigned short* Hs = (unsigned short*)lds;                 // aliases both
  __shared__ int offs[65];
  const int tid = threadIdx.x;
  const int lane = tid & 63;
  const int b = blockIdx.x;
  const int blk = b * 64;
  const int cnt = bcnt[b];

  if (tid < 65) offs[tid] = boffs[b * 65 + tid];
  for (int i = tid; i < cnt; i += 256) srcS[i] = srcsS[(size_t)b * BCAP + i];
  __syncthreads();

  // ---- gather (self from fp8 Xq)
  const int l = tid & 7, g = tid >> 3;
  const uint4* baseq = (const uint4*)Xq;
#pragma unroll
  for (int s2 = 0; s2 < 2; ++s2) {
    int nl = s2 * 32 + g;
    int node = blk + nl;
    float s[16] = {0, 0, 0, 0, 0, 0, 0, 0, 0, 0, 0, 0, 0, 0, 0, 0};
    if (node < M) {
      addf8q(s, baseq[(size_t)node * 8 + l]);
      int beg = offs[nl], c = offs[nl + 1] - beg;
      int j = 0;
      for (; j + 8 <= c; j += 8) {
        int i0 = srcS[beg + j + 0], i1 = srcS[beg + j + 1];
        int i2 = srcS[beg + j + 2], i3 = srcS[beg + j + 3];
        int i4 = srcS[beg + j + 4], i5 = srcS[beg + j + 5];
        int i6 = srcS[beg + j + 6], i7 = srcS[beg + j + 7];
        uint4 v0 = baseq[(size_t)i0 * 8 + l];
        uint4 v1 = baseq[(size_t)i1 * 8 + l];
        uint4 v2 = baseq[(size_t)i2 * 8 + l];
        uint4 v3 = baseq[(size_t)i3 * 8 + l];
        uint4 v4 = baseq[(size_t)i4 * 8 + l];
        uint4 v5 = baseq[(size_t)i5 * 8 + l];
        uint4 v6 = baseq[(size_t)i6 * 8 + l];
        uint4 v7 = baseq[(size_t)i7 * 8 + l];
        addf8q(s, v0); addf8q(s, v1); addf8q(s, v2); addf8q(s, v3);
        addf8q(s, v4); addf8q(s, v5); addf8q(s, v6); addf8q(s, v7);
      }
      if (j + 4 <= c) {
        int i0 = srcS[beg + j + 0], i1 = srcS[beg + j + 1];
        int i2 = srcS[beg + j + 2], i3 = srcS[beg + j + 3];
        uint4 v0 = baseq[(size_t)i0 * 8 + l];
        uint4 v1 = baseq[(size_t)i1 * 8 + l];
        uint4 v2 = baseq[(size_t)i2 * 8 + l];
        uint4 v3 = baseq[(size_t)i3 * 8 + l];
        addf8q(s, v0); addf8q(s, v1); addf8q(s, v2); addf8q(s, v3);
        j += 4;
      }
      if (j + 2 <= c) {
        int i0 = srcS[beg + j + 0], i1 = srcS[beg + j + 1];
        uint4 v0 = baseq[(size_t)i0 * 8 + l];
        uint4 v1 = baseq[(size_t)i1 * 8 + l];
        addf8q(s, v0); addf8q(s, v1);
        j += 2;
      }
      if (j < c) addf8q(s, baseq[(size_t)srcS[beg + j] * 8 + l]);
    }
    uint4 o0, o1;
    o0.x = pack2(s[0], s[1]);   o0.y = pack2(s[2], s[3]);
    o0.z = pack2(s[4], s[5]);   o0.w = pack2(s[6], s[7]);
    o1.x = pack2(s[8], s[9]);   o1.y = pack2(s[10], s[11]);
    o1.z = pack2(s[12], s[13]); o1.w = pack2(s[14], s[15]);
    *(uint4*)&As[nl * 136 + l * 16] = o0;
    *(uint4*)&As[nl * 136 + l * 16 + 8] = o1;
  }
  __syncthreads();

  // ---- layer-3 MFMA: 64x128, K=128; coalesced W2 frags
  const int w = tid >> 6;
  const int wm = w & 1, wn = w >> 1;
  const int l15 = lane & 15, quad = lane >> 4;
  const int mb = wm * 32, nb2 = wn * 64;

  v4f acc[2][4];
#pragma unroll
  for (int mf = 0; mf < 2; ++mf)
#pragma unroll
    for (int nf = 0; nf < 4; ++nf) acc[mf][nf] = (v4f)0.f;

#pragma unroll
  for (int k0 = 0; k0 < 128; k0 += 32) {
    const int kq = k0 >> 5;
    short8 a[2], bv[4];
#pragma unroll
    for (int mf = 0; mf < 2; ++mf)
      a[mf] = *(const short8*)&As[(mb + mf * 16 + l15) * 136 + k0 + quad * 8];
#pragma unroll
    for (int nf = 0; nf < 4; ++nf)
      bv[nf] = *(const short8*)(W2T + (size_t)(kq * 8 + wn * 4 + nf) * 512 + lane * 8);
#pragma unroll
    for (int mf = 0; mf < 2; ++mf)
#pragma unroll
      for (int nf = 0; nf < 4; ++nf)
        acc[mf][nf] = __builtin_amdgcn_mfma_f32_16x16x32_bf16(a[mf], bv[nf], acc[mf][nf], 0, 0, 0);
  }
  __syncthreads();  // all As reads done before rewrite

  // t = relu(acc + b2) -> back into As (local rows 0..63, cols 0..127)
#pragma unroll
  for (int mf = 0; mf < 2; ++mf)
#pragma unroll
    for (int r = 0; r < 4; ++r) {
      int row = mb + mf * 16 + quad * 4 + r;
#pragma unroll
      for (int nf = 0; nf < 4; ++nf) {
        int col = nb2 + nf * 16 + l15;
        As[row * 136 + col] = f2bf(fmaxf(acc[mf][nf][r] + b2[col], 0.f));
      }
    }
  __syncthreads();

  // ---- head phase A: Hm = relu(t @ Wm1 + bm1), 64x256, K=128; coalesced
  const int nbH = wn * 128;
  v4f acc2[2][8];
#pragma unroll
  for (int mf = 0; mf < 2; ++mf)
#pragma unroll
    for (int nf = 0; nf < 8; ++nf) acc2[mf][nf] = (v4f)0.f;

#pragma unroll
  for (int k0 = 0; k0 < 128; k0 += 32) {
    const int kq = k0 >> 5;
    short8 a[2];
#pragma unroll
    for (int mf = 0; mf < 2; ++mf)
      a[mf] = *(const short8*)&As[(mb + mf * 16 + l15) * 136 + k0 + quad * 8];
#pragma unroll
    for (int nf = 0; nf < 8; ++nf) {
      short8 bb = *(const short8*)(Wm1T + (size_t)(kq * 16 + wn * 8 + nf) * 512 + lane * 8);
#pragma unroll
      for (int mf = 0; mf < 2; ++mf)
        acc2[mf][nf] = __builtin_amdgcn_mfma_f32_16x16x32_bf16(a[mf], bb, acc2[mf][nf], 0, 0, 0);
    }
  }
  __syncthreads();  // As reads done; Hs may overwrite

#pragma unroll
  for (int mf = 0; mf < 2; ++mf)
#pragma unroll
    for (int r = 0; r < 4; ++r) {
      int row = mb + mf * 16 + quad * 4 + r;
#pragma unroll
      for (int nf = 0; nf < 8; ++nf) {
        int col = nbH + nf * 16 + l15;
        Hs[row * 264 + col] = f2bf(fmaxf(acc2[mf][nf][r] + bm1[col], 0.f));
      }
    }
  __syncthreads();

  // ---- head phase B: out = Hs @ Wm2 + bm2; 64x16, K=256; coalesced frags
  const int rowl = w * 16 + l15;
  v4f acc3 = (v4f)0.f;
#pragma unroll
  for (int k0 = 0; k0 < 256; k0 += 32)
    acc3 = __builtin_amdgcn_mfma_f32_16x16x32_bf16(
        *(const short8*)&Hs[rowl * 264 + k0 + quad * 8],
        *(const short8*)(Wm2T + (size_t)(k0 >> 5) * 512 + lane * 8), acc3, 0, 0, 0);
  float bb = (l15 < NOUT) ? bm2[l15] : 0.f;
#pragma unroll
  for (int r = 0; r < 4; ++r) {
    int grow = blk + w * 16 + quad * 4 + r;
    if (grow < M && l15 < NOUT) out[(size_t)grow * NOUT + l15] = acc3[r] + bb;
  }
}

// ---------------------------------------------------------------------------

extern "C" void kernel_launch(void* const* d_in, const int* in_sizes, int n_in,
                              void* d_out, int out_size, void* d_ws, size_t ws_size,
                              hipStream_t stream) {
  const float* x   = (const float*)d_in[0];
  const int*   ei  = (const int*)d_in[1];
  const float* W0  = (const float*)d_in[2];
  const float* b0  = (const float*)d_in[3];
  const float* W1  = (const float*)d_in[4];
  const float* b1  = (const float*)d_in[5];
  const float* W2  = (const float*)d_in[6];
  const float* b2  = (const float*)d_in[7];
  const float* Wm1 = (const float*)d_in[8];
  const float* bm1 = (const float*)d_in[9];
  const float* Wm2 = (const float*)d_in[10];
  const float* bm2 = (const float*)d_in[11];
  float* out = (float*)d_out;

  const int D = 128;
  const int N = in_sizes[0] / D;   // 50000
  const int E = in_sizes[1] / 2;   // 600000
  const int L = in_sizes[11];      // 10
  const int nb = (N + 63) / 64;    // 782 buckets == layer tiles

  const int* srcv = ei;
  const int* dstv = ei + E;

  char* ws = (char*)d_ws;
  size_t off = 0;
  auto alloc = [&](size_t bytes) -> void* {
    void* p = ws + off;
    off = (off + bytes + 255) & ~(size_t)255;
    return p;
  };
  int* bcnt    = (int*)alloc((size_t)MAXB * 4);
  int* bucketA = (int*)alloc((size_t)nb * BCAP * 4);
  int* srcsS   = (int*)alloc((size_t)nb * BCAP * 4);
  int* boffs   = (int*)alloc((size_t)nb * 65 * 4);
  unsigned short* xb   = (unsigned short*)alloc((size_t)N * 128 * 2);
  unsigned char*  xq   = (unsigned char*)alloc((size_t)N * 128);
  unsigned char*  h1q  = (unsigned char*)alloc((size_t)N * 128);
  unsigned char*  h2q  = (unsigned char*)alloc((size_t)N * 128);
  unsigned short* W0T  = (unsigned short*)alloc(128 * 128 * 2);
  unsigned short* W1T  = (unsigned short*)alloc(128 * 128 * 2);
  unsigned short* W2T  = (unsigned short*)alloc(128 * 128 * 2);
  unsigned short* Wm1T = (unsigned short*)alloc(256 * 128 * 2);
  unsigned short* Wm2T = (unsigned short*)alloc(16 * 256 * 2);
  (void)ws_size; (void)n_in; (void)out_size;

  const int tpb = 256;
  int n8 = N * 16;
  const int PB = (n8 + tpb - 1) / tpb;         // 3125 prep blocks
  int per = (E + NBIN - 1) / NBIN;             // 1172 edges per bin block

  hipMemsetAsync(bcnt, 0, (size_t)MAXB * 4, stream);
  prep_bin<<<dim3(PB + NBIN), dim3(tpb), 0, stream>>>(
      W0, W1, W2, Wm1, Wm2, W0T, W1T, W2T, Wm1T, Wm2T,
      x, xb, xq, n8, PB, srcv, dstv, E, per, bcnt, bucketA, nb);

  dim3 lgrid(nb);
  fused_sort_layer<<<lgrid, dim3(tpb), 0, stream>>>(
      xb, xq, bcnt, bucketA, srcsS, boffs, W0T, b0, h1q, N);  // L1 + sort
  fused_layer<<<lgrid, dim3(tpb), 0, stream>>>(
      h1q, bcnt, srcsS, boffs, W1T, b1, h2q, N);              // L2
  fused_l3_head<<<lgrid, dim3(tpb), 0, stream>>>(
      h2q, bcnt, srcsS, boffs, W2T, b2, Wm1T, bm1, Wm2T, bm2, out, N, L);
}